// Round 1
// baseline (8986.768 us; speedup 1.0000x reference)
//
#include <hip/hip_runtime.h>

// ---------------------------------------------------------------------------
// SAGEMultiSwitchModel: 2 heads x 2 SAGE layers on N=100k nodes, E=1.6M edges.
// head0 dirs "OI" (in-edges, then out-edges), head1 "UU" (undirected both).
// Layer: out = act([h | seg_mean(h)] @ [Ws|Wn]^T + b).
// Strategy: build CSR (in/out adjacency) -> wave-per-node mean aggregation ->
// fp32 LDS-tiled dual-input GEMM. h1/u1 intermediates live in d_out columns.
// ---------------------------------------------------------------------------

__global__ void k_zero(int* a, int n) {
    for (int i = blockIdx.x * blockDim.x + threadIdx.x; i < n; i += gridDim.x * blockDim.x)
        a[i] = 0;
}

__global__ void k_degrees(const int* __restrict__ src, const int* __restrict__ dst,
                          int* deg_in, int* deg_out, int E) {
    for (int e = blockIdx.x * blockDim.x + threadIdx.x; e < E; e += gridDim.x * blockDim.x) {
        atomicAdd(&deg_in[dst[e]], 1);
        atomicAdd(&deg_out[src[e]], 1);
    }
}

// exclusive scan, 1024 elems/block (256 thr x 4)
__global__ void k_scan1(const int* __restrict__ deg, int* __restrict__ excl,
                        int* __restrict__ bsums, int n) {
    __shared__ int ts[256];
    const int tid = threadIdx.x;
    const int base = blockIdx.x * 1024 + tid * 4;
    int p[4];
    int s = 0;
#pragma unroll
    for (int i = 0; i < 4; i++) {
        int v = (base + i < n) ? deg[base + i] : 0;
        p[i] = s;
        s += v;
    }
    ts[tid] = s;
    __syncthreads();
    for (int ofs = 1; ofs < 256; ofs <<= 1) {
        int t = (tid >= ofs) ? ts[tid - ofs] : 0;
        __syncthreads();
        ts[tid] += t;
        __syncthreads();
    }
    int texcl = ts[tid] - s;
#pragma unroll
    for (int i = 0; i < 4; i++)
        if (base + i < n) excl[base + i] = texcl + p[i];
    if (tid == 255) bsums[blockIdx.x] = ts[255];
}

__global__ void k_scan2(int* bsums, int nb) {
    __shared__ int ts[128];
    const int tid = threadIdx.x;
    int v = (tid < nb) ? bsums[tid] : 0;
    ts[tid] = v;
    __syncthreads();
    for (int ofs = 1; ofs < 128; ofs <<= 1) {
        int t = (tid >= ofs) ? ts[tid - ofs] : 0;
        __syncthreads();
        ts[tid] += t;
        __syncthreads();
    }
    if (tid < nb) bsums[tid] = ts[tid] - v;  // exclusive
}

__global__ void k_scan3(const int* __restrict__ excl, const int* __restrict__ bsums,
                        int* __restrict__ off, int n, int total) {
    int i = blockIdx.x * blockDim.x + threadIdx.x;
    if (i < n) off[i] = excl[i] + bsums[i >> 10];
    if (i == 0) off[n] = total;
}

__global__ void k_copy2(const int* a, int* b, const int* c, int* d, int n) {
    int i = blockIdx.x * blockDim.x + threadIdx.x;
    if (i < n) {
        b[i] = a[i];
        d[i] = c[i];
    }
}

__global__ void k_scatter(const int* __restrict__ src, const int* __restrict__ dst,
                          int* cur_in, int* cur_out, int* adj_in, int* adj_out, int E) {
    for (int e = blockIdx.x * blockDim.x + threadIdx.x; e < E; e += gridDim.x * blockDim.x) {
        int s = src[e], d = dst[e];
        adj_in[atomicAdd(&cur_in[d], 1)] = s;
        adj_out[atomicAdd(&cur_out[s], 1)] = d;
    }
}

// src [H][J][K] -> dst [H][K][J]
__global__ void k_transpose(const float* __restrict__ src, float* __restrict__ dst,
                            int J, int K, int H) {
    int total = H * J * K;
    for (int i = blockIdx.x * blockDim.x + threadIdx.x; i < total; i += gridDim.x * blockDim.x) {
        int h = i / (J * K);
        int r = i - h * (J * K);
        int j = r / K;
        int k = r - j * K;
        dst[h * K * J + k * J + j] = src[i];
    }
}

// layer-0 aggregation: F=64, wave per node; agg0 = mean over in-edges,
// aggU = mean over in+out edges (undirected).
__global__ void k_agg_l0(const float* __restrict__ x,
                         const int* __restrict__ off_in, const int* __restrict__ adj_in,
                         const int* __restrict__ off_out, const int* __restrict__ adj_out,
                         float* __restrict__ agg0, float* __restrict__ aggU, int n) {
    const int node = blockIdx.x * 4 + (threadIdx.x >> 6);
    const int lane = threadIdx.x & 63;
    if (node >= n) return;
    const int a0 = off_in[node], a1 = off_in[node + 1];
    const int b0 = off_out[node], b1 = off_out[node + 1];
    float sin_ = 0.f, sout_ = 0.f;
    for (int j = a0; j < a1; j++) sin_ += x[adj_in[j] * 64 + lane];
    for (int j = b0; j < b1; j++) sout_ += x[adj_out[j] * 64 + lane];
    const int din = a1 - a0, dout = b1 - b0;
    agg0[node * 64 + lane] = din ? sin_ / (float)din : 0.f;
    const int du = din + dout;
    aggU[node * 64 + lane] = du ? (sin_ + sout_) / (float)du : 0.f;
}

// layer-1 aggregation: F=128 (lane handles f and f+64). offB==nullptr -> single
// direction; else sum both (undirected).
__global__ void k_agg_l1(const float* __restrict__ Hf, int ldh,
                         const int* __restrict__ offA, const int* __restrict__ adjA,
                         const int* __restrict__ offB, const int* __restrict__ adjB,
                         float* __restrict__ outagg, int n) {
    const int node = blockIdx.x * 4 + (threadIdx.x >> 6);
    const int lane = threadIdx.x & 63;
    if (node >= n) return;
    float s0 = 0.f, s1 = 0.f;
    const int a0 = offA[node], a1 = offA[node + 1];
    for (int j = a0; j < a1; j++) {
        int idx = adjA[j];
        s0 += Hf[idx * ldh + lane];
        s1 += Hf[idx * ldh + lane + 64];
    }
    int deg = a1 - a0;
    if (offB) {
        const int b0 = offB[node], b1 = offB[node + 1];
        for (int j = b0; j < b1; j++) {
            int idx = adjB[j];
            s0 += Hf[idx * ldh + lane];
            s1 += Hf[idx * ldh + lane + 64];
        }
        deg += b1 - b0;
    }
    if (deg) {
        outagg[node * 128 + lane] = s0 / (float)deg;
        outagg[node * 128 + lane + 64] = s1 / (float)deg;
    } else {
        outagg[node * 128 + lane] = 0.f;
        outagg[node * 128 + lane + 64] = 0.f;
    }
}

// Out[n, 0:128] = act(A[n,:K] @ W1T + B[n,:K] @ W2T + bias)
// W1T/W2T are [K][128] (pre-transposed). BM=64 rows/block, 256 threads,
// thread = 8 rows x 4 cols, K-chunked by 32 through LDS.
__global__ void k_gemm_dual(const float* __restrict__ A, int lda,
                            const float* __restrict__ B, int ldb,
                            const float* __restrict__ W1T, const float* __restrict__ W2T,
                            const float* __restrict__ bias,
                            float* __restrict__ Out, int ldo,
                            int K, int n, int relu) {
    __shared__ float As[64 * 32];
    __shared__ float Bs[64 * 32];
    __shared__ float W1s[32 * 128];
    __shared__ float W2s[32 * 128];
    const int tid = threadIdx.x;
    const int r0 = blockIdx.x * 64;
    const int tx = tid & 31, ty = tid >> 5;
    const int j0 = tx * 4;

    float4 acc[8];
#pragma unroll
    for (int q = 0; q < 8; q++) acc[q] = make_float4(0.f, 0.f, 0.f, 0.f);

    for (int k0 = 0; k0 < K; k0 += 32) {
        // stage A,B tiles [64][32]
#pragma unroll
        for (int t = 0; t < 2; t++) {
            int f = tid + t * 256;
            int row = f >> 3, c4 = (f & 7) * 4;
            int grow = r0 + row;
            float4 av = make_float4(0.f, 0.f, 0.f, 0.f);
            float4 bv = make_float4(0.f, 0.f, 0.f, 0.f);
            if (grow < n) {
                av = *(const float4*)&A[(size_t)grow * lda + k0 + c4];
                bv = *(const float4*)&B[(size_t)grow * ldb + k0 + c4];
            }
            *(float4*)&As[row * 32 + c4] = av;
            *(float4*)&Bs[row * 32 + c4] = bv;
        }
        // stage W tiles [32][128]
#pragma unroll
        for (int t = 0; t < 4; t++) {
            int f = tid + t * 256;
            int k = f >> 5, j4 = (f & 31) * 4;
            *(float4*)&W1s[k * 128 + j4] = *(const float4*)&W1T[(size_t)(k0 + k) * 128 + j4];
            *(float4*)&W2s[k * 128 + j4] = *(const float4*)&W2T[(size_t)(k0 + k) * 128 + j4];
        }
        __syncthreads();

#pragma unroll
        for (int kk = 0; kk < 32; kk += 4) {
            float4 a[8], b[8];
#pragma unroll
            for (int q = 0; q < 8; q++) {
                int r = ty * 8 + q;
                a[q] = *(const float4*)&As[r * 32 + kk];
                b[q] = *(const float4*)&Bs[r * 32 + kk];
            }
#pragma unroll
            for (int i = 0; i < 4; i++) {
                float4 w1 = *(const float4*)&W1s[(kk + i) * 128 + j0];
                float4 w2 = *(const float4*)&W2s[(kk + i) * 128 + j0];
#pragma unroll
                for (int q = 0; q < 8; q++) {
                    float av = ((const float*)&a[q])[i];
                    float bv = ((const float*)&b[q])[i];
                    acc[q].x += av * w1.x + bv * w2.x;
                    acc[q].y += av * w1.y + bv * w2.y;
                    acc[q].z += av * w1.z + bv * w2.z;
                    acc[q].w += av * w1.w + bv * w2.w;
                }
            }
        }
        __syncthreads();
    }

    const float4 bv4 = *(const float4*)&bias[j0];
#pragma unroll
    for (int q = 0; q < 8; q++) {
        int grow = r0 + ty * 8 + q;
        if (grow < n) {
            float4 o;
            o.x = acc[q].x + bv4.x;
            o.y = acc[q].y + bv4.y;
            o.z = acc[q].z + bv4.z;
            o.w = acc[q].w + bv4.w;
            if (relu) {
                o.x = fmaxf(o.x, 0.f);
                o.y = fmaxf(o.y, 0.f);
                o.z = fmaxf(o.z, 0.f);
                o.w = fmaxf(o.w, 0.f);
            }
            *(float4*)&Out[(size_t)grow * ldo + j0] = o;
        }
    }
}

extern "C" void kernel_launch(void* const* d_in, const int* in_sizes, int n_in,
                              void* d_out, int out_size, void* d_ws, size_t ws_size,
                              hipStream_t stream) {
    const float* x = (const float*)d_in[0];
    const int* src = (const int*)d_in[1];
    const int* dst = (const int*)d_in[2];
    const float* Wn0 = (const float*)d_in[3];
    const float* Ws0 = (const float*)d_in[4];
    const float* b0 = (const float*)d_in[5];
    const float* Wn1 = (const float*)d_in[6];
    const float* Ws1 = (const float*)d_in[7];
    const float* b1 = (const float*)d_in[8];

    const int N = in_sizes[0] / 64;
    const int E = in_sizes[1];
    float* out = (float*)d_out;

    // ---- workspace layout ----
    char* w = (char*)d_ws;
    size_t o = 0;
    auto alloc = [&](size_t bytes) -> void* {
        o = (o + 255) & ~(size_t)255;
        void* p = w + o;
        o += bytes;
        return p;
    };
    int* deg_in = (int*)alloc((size_t)N * 4);
    int* deg_out = (int*)alloc((size_t)N * 4);
    int* off_in = (int*)alloc((size_t)(N + 1) * 4);
    int* off_out = (int*)alloc((size_t)(N + 1) * 4);
    int* cur_in = (int*)alloc((size_t)N * 4);
    int* cur_out = (int*)alloc((size_t)N * 4);
    int* excl = (int*)alloc((size_t)N * 4);
    int* bsums = (int*)alloc(1024 * 4);
    int* adj_in = (int*)alloc((size_t)E * 4);
    int* adj_out = (int*)alloc((size_t)E * 4);
    float* AGG = (float*)alloc((size_t)N * 128 * 4);  // also holds agg0|aggU (N*64 each) for L0
    float* WsT0 = (float*)alloc(2 * 64 * 128 * 4);
    float* WnT0 = (float*)alloc(2 * 64 * 128 * 4);
    float* WsT1 = (float*)alloc(2 * 128 * 128 * 4);
    float* WnT1 = (float*)alloc(2 * 128 * 128 * 4);
    (void)ws_size;

    const int nb1 = (N + 1023) / 1024;  // scan blocks (98) — must be <= 128

    // ---- weight pre-transpose (independent of graph build) ----
    k_transpose<<<64, 256, 0, stream>>>(Ws0, WsT0, 128, 64, 2);
    k_transpose<<<64, 256, 0, stream>>>(Wn0, WnT0, 128, 64, 2);
    k_transpose<<<128, 256, 0, stream>>>(Ws1, WsT1, 128, 128, 2);
    k_transpose<<<128, 256, 0, stream>>>(Wn1, WnT1, 128, 128, 2);

    // ---- CSR build ----
    k_zero<<<(N + 255) / 256, 256, 0, stream>>>(deg_in, N);
    k_zero<<<(N + 255) / 256, 256, 0, stream>>>(deg_out, N);
    k_degrees<<<(E + 255) / 256, 256, 0, stream>>>(src, dst, deg_in, deg_out, E);

    k_scan1<<<nb1, 256, 0, stream>>>(deg_in, excl, bsums, N);
    k_scan2<<<1, 128, 0, stream>>>(bsums, nb1);
    k_scan3<<<(N + 255) / 256, 256, 0, stream>>>(excl, bsums, off_in, N, E);

    k_scan1<<<nb1, 256, 0, stream>>>(deg_out, excl, bsums, N);
    k_scan2<<<1, 128, 0, stream>>>(bsums, nb1);
    k_scan3<<<(N + 255) / 256, 256, 0, stream>>>(excl, bsums, off_out, N, E);

    k_copy2<<<(N + 255) / 256, 256, 0, stream>>>(off_in, cur_in, off_out, cur_out, N);
    k_scatter<<<(E + 255) / 256, 256, 0, stream>>>(src, dst, cur_in, cur_out, adj_in, adj_out, E);

    const int nodeBlocks = (N + 3) / 4;
    const int gemmBlocks = (N + 63) / 64;

    // ---- layer 0 ----
    float* agg0 = AGG;                      // [N,64]
    float* aggU = AGG + (size_t)N * 64;     // [N,64]
    k_agg_l0<<<nodeBlocks, 256, 0, stream>>>(x, off_in, adj_in, off_out, adj_out, agg0, aggU, N);
    // head0 -> d_out cols 0:128 (h1), relu
    k_gemm_dual<<<gemmBlocks, 256, 0, stream>>>(x, 64, agg0, 64, WsT0, WnT0, b0, out, 256, 64, N, 1);
    // head1 -> d_out cols 128:256 (u1), relu
    k_gemm_dual<<<gemmBlocks, 256, 0, stream>>>(x, 64, aggU, 64, WsT0 + 64 * 128, WnT0 + 64 * 128,
                                                b0 + 128, out + 128, 256, 64, N, 1);

    // ---- layer 1 ----
    // head0: 'I' -> aggregate h1 over out-edges
    k_agg_l1<<<nodeBlocks, 256, 0, stream>>>(out, 256, off_out, adj_out, (const int*)nullptr,
                                             (const int*)nullptr, AGG, N);
    k_gemm_dual<<<gemmBlocks, 256, 0, stream>>>(out, 256, AGG, 128, WsT1, WnT1, b1, out, 256, 128, N, 0);
    // head1: 'U' -> aggregate u1 over in+out edges
    k_agg_l1<<<nodeBlocks, 256, 0, stream>>>(out + 128, 256, off_in, adj_in, off_out, adj_out, AGG, N);
    k_gemm_dual<<<gemmBlocks, 256, 0, stream>>>(out + 128, 256, AGG, 128, WsT1 + 128 * 128,
                                                WnT1 + 128 * 128, b1 + 128, out + 128, 256, 128, N, 0);
}

// Round 2
// 1468.208 us; speedup vs baseline: 6.1209x; 6.1209x over previous
//
#include <hip/hip_runtime.h>

// ---------------------------------------------------------------------------
// SAGEMultiSwitchModel: 2 heads x 2 SAGE layers on N=100k nodes, E=1.6M edges.
// head0 dirs "OI" (in-edges, then out-edges), head1 "UU" (undirected both).
// Layer: out = act([h | seg_mean(h)] @ [Ws|Wn]^T + b).
// Strategy: build CSR (in/out adjacency) -> wave-per-node mean aggregation ->
// fp32 LDS-tiled dual-input GEMM. h1/u1 intermediates live in d_out columns.
// R1: gemm inner loop rewritten spill-free (no address-taken float4 elements,
//     __launch_bounds__(256)) — was 9 GB scratch traffic per dispatch.
// ---------------------------------------------------------------------------

__global__ void k_zero(int* a, int n) {
    for (int i = blockIdx.x * blockDim.x + threadIdx.x; i < n; i += gridDim.x * blockDim.x)
        a[i] = 0;
}

__global__ void k_degrees(const int* __restrict__ src, const int* __restrict__ dst,
                          int* deg_in, int* deg_out, int E) {
    for (int e = blockIdx.x * blockDim.x + threadIdx.x; e < E; e += gridDim.x * blockDim.x) {
        atomicAdd(&deg_in[dst[e]], 1);
        atomicAdd(&deg_out[src[e]], 1);
    }
}

// exclusive scan, 1024 elems/block (256 thr x 4)
__global__ void k_scan1(const int* __restrict__ deg, int* __restrict__ excl,
                        int* __restrict__ bsums, int n) {
    __shared__ int ts[256];
    const int tid = threadIdx.x;
    const int base = blockIdx.x * 1024 + tid * 4;
    int p[4];
    int s = 0;
#pragma unroll
    for (int i = 0; i < 4; i++) {
        int v = (base + i < n) ? deg[base + i] : 0;
        p[i] = s;
        s += v;
    }
    ts[tid] = s;
    __syncthreads();
    for (int ofs = 1; ofs < 256; ofs <<= 1) {
        int t = (tid >= ofs) ? ts[tid - ofs] : 0;
        __syncthreads();
        ts[tid] += t;
        __syncthreads();
    }
    int texcl = ts[tid] - s;
#pragma unroll
    for (int i = 0; i < 4; i++)
        if (base + i < n) excl[base + i] = texcl + p[i];
    if (tid == 255) bsums[blockIdx.x] = ts[255];
}

__global__ void k_scan2(int* bsums, int nb) {
    __shared__ int ts[128];
    const int tid = threadIdx.x;
    int v = (tid < nb) ? bsums[tid] : 0;
    ts[tid] = v;
    __syncthreads();
    for (int ofs = 1; ofs < 128; ofs <<= 1) {
        int t = (tid >= ofs) ? ts[tid - ofs] : 0;
        __syncthreads();
        ts[tid] += t;
        __syncthreads();
    }
    if (tid < nb) bsums[tid] = ts[tid] - v;  // exclusive
}

__global__ void k_scan3(const int* __restrict__ excl, const int* __restrict__ bsums,
                        int* __restrict__ off, int n, int total) {
    int i = blockIdx.x * blockDim.x + threadIdx.x;
    if (i < n) off[i] = excl[i] + bsums[i >> 10];
    if (i == 0) off[n] = total;
}

__global__ void k_copy2(const int* a, int* b, const int* c, int* d, int n) {
    int i = blockIdx.x * blockDim.x + threadIdx.x;
    if (i < n) {
        b[i] = a[i];
        d[i] = c[i];
    }
}

__global__ void k_scatter(const int* __restrict__ src, const int* __restrict__ dst,
                          int* cur_in, int* cur_out, int* adj_in, int* adj_out, int E) {
    for (int e = blockIdx.x * blockDim.x + threadIdx.x; e < E; e += gridDim.x * blockDim.x) {
        int s = src[e], d = dst[e];
        adj_in[atomicAdd(&cur_in[d], 1)] = s;
        adj_out[atomicAdd(&cur_out[s], 1)] = d;
    }
}

// src [H][J][K] -> dst [H][K][J]
__global__ void k_transpose(const float* __restrict__ src, float* __restrict__ dst,
                            int J, int K, int H) {
    int total = H * J * K;
    for (int i = blockIdx.x * blockDim.x + threadIdx.x; i < total; i += gridDim.x * blockDim.x) {
        int h = i / (J * K);
        int r = i - h * (J * K);
        int j = r / K;
        int k = r - j * K;
        dst[h * K * J + k * J + j] = src[i];
    }
}

// layer-0 aggregation: F=64, wave per node; agg0 = mean over in-edges,
// aggU = mean over in+out edges (undirected).
__global__ void __launch_bounds__(256) k_agg_l0(
        const float* __restrict__ x,
        const int* __restrict__ off_in, const int* __restrict__ adj_in,
        const int* __restrict__ off_out, const int* __restrict__ adj_out,
        float* __restrict__ agg0, float* __restrict__ aggU, int n) {
    const int node = blockIdx.x * 4 + (threadIdx.x >> 6);
    const int lane = threadIdx.x & 63;
    if (node >= n) return;
    const int a0 = off_in[node], a1 = off_in[node + 1];
    const int b0 = off_out[node], b1 = off_out[node + 1];
    float sin_ = 0.f, sout_ = 0.f;
    for (int j = a0; j < a1; j++) sin_ += x[adj_in[j] * 64 + lane];
    for (int j = b0; j < b1; j++) sout_ += x[adj_out[j] * 64 + lane];
    const int din = a1 - a0, dout = b1 - b0;
    agg0[node * 64 + lane] = din ? sin_ / (float)din : 0.f;
    const int du = din + dout;
    aggU[node * 64 + lane] = du ? (sin_ + sout_) / (float)du : 0.f;
}

// layer-1 aggregation: F=128 (lane handles f and f+64). offB==nullptr -> single
// direction; else sum both (undirected).
__global__ void __launch_bounds__(256) k_agg_l1(
        const float* __restrict__ Hf, int ldh,
        const int* __restrict__ offA, const int* __restrict__ adjA,
        const int* __restrict__ offB, const int* __restrict__ adjB,
        float* __restrict__ outagg, int n) {
    const int node = blockIdx.x * 4 + (threadIdx.x >> 6);
    const int lane = threadIdx.x & 63;
    if (node >= n) return;
    float s0 = 0.f, s1 = 0.f;
    const int a0 = offA[node], a1 = offA[node + 1];
    for (int j = a0; j < a1; j++) {
        int idx = adjA[j];
        s0 += Hf[idx * ldh + lane];
        s1 += Hf[idx * ldh + lane + 64];
    }
    int deg = a1 - a0;
    if (offB) {
        const int b0 = offB[node], b1 = offB[node + 1];
        for (int j = b0; j < b1; j++) {
            int idx = adjB[j];
            s0 += Hf[idx * ldh + lane];
            s1 += Hf[idx * ldh + lane + 64];
        }
        deg += b1 - b0;
    }
    if (deg) {
        outagg[node * 128 + lane] = s0 / (float)deg;
        outagg[node * 128 + lane + 64] = s1 / (float)deg;
    } else {
        outagg[node * 128 + lane] = 0.f;
        outagg[node * 128 + lane + 64] = 0.f;
    }
}

// Out[n, 0:128] = act(A[n,:K] @ W1T + B[n,:K] @ W2T + bias)
// W1T/W2T are [K][128] (pre-transposed). BM=64 rows/block, 256 threads,
// thread = 8 rows x 4 cols, K-chunked by 32 through LDS.
// Spill-free: named float4 registers only, no address-taken vector elements.
#define FMA4(q, av, wv)        \
    acc[q].x += (av) * wv.x;   \
    acc[q].y += (av) * wv.y;   \
    acc[q].z += (av) * wv.z;   \
    acc[q].w += (av) * wv.w;

__global__ void __launch_bounds__(256) k_gemm_dual(
        const float* __restrict__ A, int lda,
        const float* __restrict__ B, int ldb,
        const float* __restrict__ W1T, const float* __restrict__ W2T,
        const float* __restrict__ bias,
        float* __restrict__ Out, int ldo,
        int K, int n, int relu) {
    __shared__ float As[64 * 32];
    __shared__ float Bs[64 * 32];
    __shared__ float W1s[32 * 128];
    __shared__ float W2s[32 * 128];
    const int tid = threadIdx.x;
    const int r0 = blockIdx.x * 64;
    const int tx = tid & 31, ty = tid >> 5;
    const int j0 = tx * 4;

    float4 acc[8];
#pragma unroll
    for (int q = 0; q < 8; q++) acc[q] = make_float4(0.f, 0.f, 0.f, 0.f);

    for (int k0 = 0; k0 < K; k0 += 32) {
        // stage A,B tiles [64][32]
#pragma unroll
        for (int t = 0; t < 2; t++) {
            int f = tid + t * 256;
            int row = f >> 3, c4 = (f & 7) * 4;
            int grow = r0 + row;
            float4 av = make_float4(0.f, 0.f, 0.f, 0.f);
            float4 bv = make_float4(0.f, 0.f, 0.f, 0.f);
            if (grow < n) {
                av = *(const float4*)&A[(size_t)grow * lda + k0 + c4];
                bv = *(const float4*)&B[(size_t)grow * ldb + k0 + c4];
            }
            *(float4*)&As[row * 32 + c4] = av;
            *(float4*)&Bs[row * 32 + c4] = bv;
        }
        // stage W tiles [32][128]
#pragma unroll
        for (int t = 0; t < 4; t++) {
            int f = tid + t * 256;
            int k = f >> 5, j4 = (f & 31) * 4;
            *(float4*)&W1s[k * 128 + j4] = *(const float4*)&W1T[(size_t)(k0 + k) * 128 + j4];
            *(float4*)&W2s[k * 128 + j4] = *(const float4*)&W2T[(size_t)(k0 + k) * 128 + j4];
        }
        __syncthreads();

#pragma unroll
        for (int kk = 0; kk < 32; kk += 4) {
            const float4 w1a = *(const float4*)&W1s[(kk + 0) * 128 + j0];
            const float4 w1b = *(const float4*)&W1s[(kk + 1) * 128 + j0];
            const float4 w1c = *(const float4*)&W1s[(kk + 2) * 128 + j0];
            const float4 w1d = *(const float4*)&W1s[(kk + 3) * 128 + j0];
            const float4 w2a = *(const float4*)&W2s[(kk + 0) * 128 + j0];
            const float4 w2b = *(const float4*)&W2s[(kk + 1) * 128 + j0];
            const float4 w2c = *(const float4*)&W2s[(kk + 2) * 128 + j0];
            const float4 w2d = *(const float4*)&W2s[(kk + 3) * 128 + j0];
#pragma unroll
            for (int q = 0; q < 8; q++) {
                const int r = ty * 8 + q;
                const float4 a = *(const float4*)&As[r * 32 + kk];
                const float4 b = *(const float4*)&Bs[r * 32 + kk];
                FMA4(q, a.x, w1a)
                FMA4(q, a.y, w1b)
                FMA4(q, a.z, w1c)
                FMA4(q, a.w, w1d)
                FMA4(q, b.x, w2a)
                FMA4(q, b.y, w2b)
                FMA4(q, b.z, w2c)
                FMA4(q, b.w, w2d)
            }
        }
        __syncthreads();
    }

    const float4 bv4 = *(const float4*)&bias[j0];
#pragma unroll
    for (int q = 0; q < 8; q++) {
        int grow = r0 + ty * 8 + q;
        if (grow < n) {
            float4 o;
            o.x = acc[q].x + bv4.x;
            o.y = acc[q].y + bv4.y;
            o.z = acc[q].z + bv4.z;
            o.w = acc[q].w + bv4.w;
            if (relu) {
                o.x = fmaxf(o.x, 0.f);
                o.y = fmaxf(o.y, 0.f);
                o.z = fmaxf(o.z, 0.f);
                o.w = fmaxf(o.w, 0.f);
            }
            *(float4*)&Out[(size_t)grow * ldo + j0] = o;
        }
    }
}

extern "C" void kernel_launch(void* const* d_in, const int* in_sizes, int n_in,
                              void* d_out, int out_size, void* d_ws, size_t ws_size,
                              hipStream_t stream) {
    const float* x = (const float*)d_in[0];
    const int* src = (const int*)d_in[1];
    const int* dst = (const int*)d_in[2];
    const float* Wn0 = (const float*)d_in[3];
    const float* Ws0 = (const float*)d_in[4];
    const float* b0 = (const float*)d_in[5];
    const float* Wn1 = (const float*)d_in[6];
    const float* Ws1 = (const float*)d_in[7];
    const float* b1 = (const float*)d_in[8];

    const int N = in_sizes[0] / 64;
    const int E = in_sizes[1];
    float* out = (float*)d_out;

    // ---- workspace layout ----
    char* w = (char*)d_ws;
    size_t o = 0;
    auto alloc = [&](size_t bytes) -> void* {
        o = (o + 255) & ~(size_t)255;
        void* p = w + o;
        o += bytes;
        return p;
    };
    int* deg_in = (int*)alloc((size_t)N * 4);
    int* deg_out = (int*)alloc((size_t)N * 4);
    int* off_in = (int*)alloc((size_t)(N + 1) * 4);
    int* off_out = (int*)alloc((size_t)(N + 1) * 4);
    int* cur_in = (int*)alloc((size_t)N * 4);
    int* cur_out = (int*)alloc((size_t)N * 4);
    int* excl = (int*)alloc((size_t)N * 4);
    int* bsums = (int*)alloc(1024 * 4);
    int* adj_in = (int*)alloc((size_t)E * 4);
    int* adj_out = (int*)alloc((size_t)E * 4);
    float* AGG = (float*)alloc((size_t)N * 128 * 4);  // also holds agg0|aggU (N*64 each) for L0
    float* WsT0 = (float*)alloc(2 * 64 * 128 * 4);
    float* WnT0 = (float*)alloc(2 * 64 * 128 * 4);
    float* WsT1 = (float*)alloc(2 * 128 * 128 * 4);
    float* WnT1 = (float*)alloc(2 * 128 * 128 * 4);
    (void)ws_size;

    const int nb1 = (N + 1023) / 1024;  // scan blocks (98) — must be <= 128

    // ---- weight pre-transpose (independent of graph build) ----
    k_transpose<<<64, 256, 0, stream>>>(Ws0, WsT0, 128, 64, 2);
    k_transpose<<<64, 256, 0, stream>>>(Wn0, WnT0, 128, 64, 2);
    k_transpose<<<128, 256, 0, stream>>>(Ws1, WsT1, 128, 128, 2);
    k_transpose<<<128, 256, 0, stream>>>(Wn1, WnT1, 128, 128, 2);

    // ---- CSR build ----
    k_zero<<<(N + 255) / 256, 256, 0, stream>>>(deg_in, N);
    k_zero<<<(N + 255) / 256, 256, 0, stream>>>(deg_out, N);
    k_degrees<<<(E + 255) / 256, 256, 0, stream>>>(src, dst, deg_in, deg_out, E);

    k_scan1<<<nb1, 256, 0, stream>>>(deg_in, excl, bsums, N);
    k_scan2<<<1, 128, 0, stream>>>(bsums, nb1);
    k_scan3<<<(N + 255) / 256, 256, 0, stream>>>(excl, bsums, off_in, N, E);

    k_scan1<<<nb1, 256, 0, stream>>>(deg_out, excl, bsums, N);
    k_scan2<<<1, 128, 0, stream>>>(bsums, nb1);
    k_scan3<<<(N + 255) / 256, 256, 0, stream>>>(excl, bsums, off_out, N, E);

    k_copy2<<<(N + 255) / 256, 256, 0, stream>>>(off_in, cur_in, off_out, cur_out, N);
    k_scatter<<<(E + 255) / 256, 256, 0, stream>>>(src, dst, cur_in, cur_out, adj_in, adj_out, E);

    const int nodeBlocks = (N + 3) / 4;
    const int gemmBlocks = (N + 63) / 64;

    // ---- layer 0 ----
    float* agg0 = AGG;                      // [N,64]
    float* aggU = AGG + (size_t)N * 64;     // [N,64]
    k_agg_l0<<<nodeBlocks, 256, 0, stream>>>(x, off_in, adj_in, off_out, adj_out, agg0, aggU, N);
    // head0 -> d_out cols 0:128 (h1), relu
    k_gemm_dual<<<gemmBlocks, 256, 0, stream>>>(x, 64, agg0, 64, WsT0, WnT0, b0, out, 256, 64, N, 1);
    // head1 -> d_out cols 128:256 (u1), relu
    k_gemm_dual<<<gemmBlocks, 256, 0, stream>>>(x, 64, aggU, 64, WsT0 + 64 * 128, WnT0 + 64 * 128,
                                                b0 + 128, out + 128, 256, 64, N, 1);

    // ---- layer 1 ----
    // head0: 'I' -> aggregate h1 over out-edges
    k_agg_l1<<<nodeBlocks, 256, 0, stream>>>(out, 256, off_out, adj_out, (const int*)nullptr,
                                             (const int*)nullptr, AGG, N);
    k_gemm_dual<<<gemmBlocks, 256, 0, stream>>>(out, 256, AGG, 128, WsT1, WnT1, b1, out, 256, 128, N, 0);
    // head1: 'U' -> aggregate u1 over in+out edges
    k_agg_l1<<<nodeBlocks, 256, 0, stream>>>(out + 128, 256, off_in, adj_in, off_out, adj_out, AGG, N);
    k_gemm_dual<<<gemmBlocks, 256, 0, stream>>>(out + 128, 256, AGG, 128, WsT1 + 128 * 128,
                                                WnT1 + 128 * 128, b1 + 128, out + 128, 256, 128, N, 0);
}

// Round 3
// 1225.379 us; speedup vs baseline: 7.3339x; 1.1982x over previous
//
#include <hip/hip_runtime.h>

// ---------------------------------------------------------------------------
// SAGEMultiSwitchModel: 2 heads x 2 SAGE layers on N=100k nodes, E=1.6M edges.
// head0 dirs "OI" (in-edges, then out-edges), head1 "UU" (undirected both).
// Layer: out = act([h | seg_mean(h)] @ [Ws|Wn]^T + b).
// R1: spill-free fp32 gemm (was 9 GB scratch traffic/dispatch).
// R2: bf16 side tables for all gathered/streamed intermediates (xb, h1b, u1b,
//     agg) — halves gather traffic, which dominates (agg_l1 = 2x302us @0.82GB).
//     GEMM stages bf16 -> fp32 LDS; inner loop & accumulation stay fp32.
//     xb lives in d_out scratch (dead before final L1 gemm writes).
// ---------------------------------------------------------------------------

typedef unsigned short u16;
typedef unsigned int u32;

__device__ __forceinline__ u32 f2bf(float f) {  // RNE float->bf16 (low 16 bits)
    u32 u = __float_as_uint(f);
    return (u + 0x7fffu + ((u >> 16) & 1u)) >> 16;
}
__device__ __forceinline__ float bf_lo(u32 v) { return __uint_as_float(v << 16); }
__device__ __forceinline__ float bf_hi(u32 v) { return __uint_as_float(v & 0xffff0000u); }

__global__ void k_zero(int* a, int n) {
    for (int i = blockIdx.x * blockDim.x + threadIdx.x; i < n; i += gridDim.x * blockDim.x)
        a[i] = 0;
}

__global__ void k_cvt_bf16(const float* __restrict__ in, u16* __restrict__ out, int n4) {
    int i = blockIdx.x * blockDim.x + threadIdx.x;
    if (i >= n4) return;
    float4 v = *(const float4*)&in[(size_t)i * 4];
    u32 p0 = f2bf(v.x) | (f2bf(v.y) << 16);
    u32 p1 = f2bf(v.z) | (f2bf(v.w) << 16);
    *(uint2*)&out[(size_t)i * 4] = make_uint2(p0, p1);
}

__global__ void k_degrees(const int* __restrict__ src, const int* __restrict__ dst,
                          int* deg_in, int* deg_out, int E) {
    for (int e = blockIdx.x * blockDim.x + threadIdx.x; e < E; e += gridDim.x * blockDim.x) {
        atomicAdd(&deg_in[dst[e]], 1);
        atomicAdd(&deg_out[src[e]], 1);
    }
}

// exclusive scan, 1024 elems/block (256 thr x 4)
__global__ void k_scan1(const int* __restrict__ deg, int* __restrict__ excl,
                        int* __restrict__ bsums, int n) {
    __shared__ int ts[256];
    const int tid = threadIdx.x;
    const int base = blockIdx.x * 1024 + tid * 4;
    int p[4];
    int s = 0;
#pragma unroll
    for (int i = 0; i < 4; i++) {
        int v = (base + i < n) ? deg[base + i] : 0;
        p[i] = s;
        s += v;
    }
    ts[tid] = s;
    __syncthreads();
    for (int ofs = 1; ofs < 256; ofs <<= 1) {
        int t = (tid >= ofs) ? ts[tid - ofs] : 0;
        __syncthreads();
        ts[tid] += t;
        __syncthreads();
    }
    int texcl = ts[tid] - s;
#pragma unroll
    for (int i = 0; i < 4; i++)
        if (base + i < n) excl[base + i] = texcl + p[i];
    if (tid == 255) bsums[blockIdx.x] = ts[255];
}

__global__ void k_scan2(int* bsums, int nb) {
    __shared__ int ts[128];
    const int tid = threadIdx.x;
    int v = (tid < nb) ? bsums[tid] : 0;
    ts[tid] = v;
    __syncthreads();
    for (int ofs = 1; ofs < 128; ofs <<= 1) {
        int t = (tid >= ofs) ? ts[tid - ofs] : 0;
        __syncthreads();
        ts[tid] += t;
        __syncthreads();
    }
    if (tid < nb) bsums[tid] = ts[tid] - v;  // exclusive
}

__global__ void k_scan3(const int* __restrict__ excl, const int* __restrict__ bsums,
                        int* __restrict__ off, int n, int total) {
    int i = blockIdx.x * blockDim.x + threadIdx.x;
    if (i < n) off[i] = excl[i] + bsums[i >> 10];
    if (i == 0) off[n] = total;
}

__global__ void k_copy2(const int* a, int* b, const int* c, int* d, int n) {
    int i = blockIdx.x * blockDim.x + threadIdx.x;
    if (i < n) {
        b[i] = a[i];
        d[i] = c[i];
    }
}

__global__ void k_scatter(const int* __restrict__ src, const int* __restrict__ dst,
                          int* cur_in, int* cur_out, int* adj_in, int* adj_out, int E) {
    for (int e = blockIdx.x * blockDim.x + threadIdx.x; e < E; e += gridDim.x * blockDim.x) {
        int s = src[e], d = dst[e];
        adj_in[atomicAdd(&cur_in[d], 1)] = s;
        adj_out[atomicAdd(&cur_out[s], 1)] = d;
    }
}

// src [H][J][K] -> dst [H][K][J]
__global__ void k_transpose(const float* __restrict__ src, float* __restrict__ dst,
                            int J, int K, int H) {
    int total = H * J * K;
    for (int i = blockIdx.x * blockDim.x + threadIdx.x; i < total; i += gridDim.x * blockDim.x) {
        int h = i / (J * K);
        int r = i - h * (J * K);
        int j = r / K;
        int k = r - j * K;
        dst[h * K * J + k * J + j] = src[i];
    }
}

// layer-0 aggregation: F=64 bf16 gather, wave per node; agg0 = mean over
// in-edges, aggU = mean over in+out edges. Outputs bf16 [n][64].
__global__ void __launch_bounds__(256) k_agg_l0_b(
        const u16* __restrict__ xb,
        const int* __restrict__ off_in, const int* __restrict__ adj_in,
        const int* __restrict__ off_out, const int* __restrict__ adj_out,
        u16* __restrict__ agg0b, u16* __restrict__ aggUb, int n) {
    const int node = blockIdx.x * 4 + (threadIdx.x >> 6);
    const int lane = threadIdx.x & 63;
    if (node >= n) return;
    const int a0 = off_in[node], a1 = off_in[node + 1];
    const int b0 = off_out[node], b1 = off_out[node + 1];
    float sin_ = 0.f, sout_ = 0.f;
    int j = a0;
    for (; j + 1 < a1; j += 2) {
        int i0 = adj_in[j], i1 = adj_in[j + 1];
        float v0 = bf_lo((u32)xb[(size_t)i0 * 64 + lane]);
        float v1 = bf_lo((u32)xb[(size_t)i1 * 64 + lane]);
        sin_ += v0 + v1;
    }
    if (j < a1) sin_ += bf_lo((u32)xb[(size_t)adj_in[j] * 64 + lane]);
    j = b0;
    for (; j + 1 < b1; j += 2) {
        int i0 = adj_out[j], i1 = adj_out[j + 1];
        float v0 = bf_lo((u32)xb[(size_t)i0 * 64 + lane]);
        float v1 = bf_lo((u32)xb[(size_t)i1 * 64 + lane]);
        sout_ += v0 + v1;
    }
    if (j < b1) sout_ += bf_lo((u32)xb[(size_t)adj_out[j] * 64 + lane]);
    const int din = a1 - a0, dout = b1 - b0;
    const int du = din + dout;
    agg0b[(size_t)node * 64 + lane] = (u16)f2bf(din ? sin_ / (float)din : 0.f);
    aggUb[(size_t)node * 64 + lane] = (u16)f2bf(du ? (sin_ + sout_) / (float)du : 0.f);
}

// layer-1 aggregation: F=128 bf16 gather (lane reads packed pair 2l,2l+1).
// offB==nullptr -> single direction; else undirected. Output bf16 [n][128].
__global__ void __launch_bounds__(256) k_agg_l1_b(
        const u16* __restrict__ Hb,
        const int* __restrict__ offA, const int* __restrict__ adjA,
        const int* __restrict__ offB, const int* __restrict__ adjB,
        u16* __restrict__ outb, int n) {
    const int node = blockIdx.x * 4 + (threadIdx.x >> 6);
    const int lane = threadIdx.x & 63;
    if (node >= n) return;
    float s0 = 0.f, s1 = 0.f;
    const int a0 = offA[node], a1 = offA[node + 1];
    int j = a0;
    for (; j + 1 < a1; j += 2) {
        int i0 = adjA[j], i1 = adjA[j + 1];
        u32 v0 = *(const u32*)&Hb[(size_t)i0 * 128 + lane * 2];
        u32 v1 = *(const u32*)&Hb[(size_t)i1 * 128 + lane * 2];
        s0 += bf_lo(v0) + bf_lo(v1);
        s1 += bf_hi(v0) + bf_hi(v1);
    }
    if (j < a1) {
        u32 v = *(const u32*)&Hb[(size_t)adjA[j] * 128 + lane * 2];
        s0 += bf_lo(v);
        s1 += bf_hi(v);
    }
    int deg = a1 - a0;
    if (offB) {
        const int b0 = offB[node], b1 = offB[node + 1];
        j = b0;
        for (; j + 1 < b1; j += 2) {
            int i0 = adjB[j], i1 = adjB[j + 1];
            u32 v0 = *(const u32*)&Hb[(size_t)i0 * 128 + lane * 2];
            u32 v1 = *(const u32*)&Hb[(size_t)i1 * 128 + lane * 2];
            s0 += bf_lo(v0) + bf_lo(v1);
            s1 += bf_hi(v0) + bf_hi(v1);
        }
        if (j < b1) {
            u32 v = *(const u32*)&Hb[(size_t)adjB[j] * 128 + lane * 2];
            s0 += bf_lo(v);
            s1 += bf_hi(v);
        }
        deg += b1 - b0;
    }
    float inv = deg ? 1.f / (float)deg : 0.f;
    u32 p = f2bf(s0 * inv) | (f2bf(s1 * inv) << 16);
    *(u32*)&outb[(size_t)node * 128 + lane * 2] = p;
}

// Out[n, 0:128] = act(A[n,:K] @ W1T + B[n,:K] @ W2T + bias)
// A,B are packed bf16 [*, K]; W1T/W2T are fp32 [K][128] (pre-transposed).
// BM=64 rows/block, 256 threads, thread = 8 rows x 4 cols, K-chunk 32 via LDS.
// OUT_BF16=1 -> packed bf16 [*,128] table; else fp32 with row stride ldo.
#define FMA4(q, av, wv)        \
    acc[q].x += (av) * wv.x;   \
    acc[q].y += (av) * wv.y;   \
    acc[q].z += (av) * wv.z;   \
    acc[q].w += (av) * wv.w;

template <int OUT_BF16>
__global__ void __launch_bounds__(256) k_gemm_dual_b(
        const u16* __restrict__ A, int lda,
        const u16* __restrict__ B, int ldb,
        const float* __restrict__ W1T, const float* __restrict__ W2T,
        const float* __restrict__ bias,
        float* __restrict__ OutF, int ldo, u16* __restrict__ OutB,
        int K, int n, int relu) {
    __shared__ float As[64 * 32];
    __shared__ float Bs[64 * 32];
    __shared__ float W1s[32 * 128];
    __shared__ float W2s[32 * 128];
    const int tid = threadIdx.x;
    const int r0 = blockIdx.x * 64;
    const int tx = tid & 31, ty = tid >> 5;
    const int j0 = tx * 4;
    // staging coords: each thread stages 8 ushorts (one uint4) of A and of B
    const int srow = tid >> 2, sseg = (tid & 3) * 8;

    float4 acc[8];
#pragma unroll
    for (int q = 0; q < 8; q++) acc[q] = make_float4(0.f, 0.f, 0.f, 0.f);

    for (int k0 = 0; k0 < K; k0 += 32) {
        {
            const int grow = r0 + srow;
            uint4 av = make_uint4(0, 0, 0, 0), bv = make_uint4(0, 0, 0, 0);
            if (grow < n) {
                av = *(const uint4*)&A[(size_t)grow * lda + k0 + sseg];
                bv = *(const uint4*)&B[(size_t)grow * ldb + k0 + sseg];
            }
            float4 f;
            f.x = bf_lo(av.x); f.y = bf_hi(av.x); f.z = bf_lo(av.y); f.w = bf_hi(av.y);
            *(float4*)&As[srow * 32 + sseg] = f;
            f.x = bf_lo(av.z); f.y = bf_hi(av.z); f.z = bf_lo(av.w); f.w = bf_hi(av.w);
            *(float4*)&As[srow * 32 + sseg + 4] = f;
            f.x = bf_lo(bv.x); f.y = bf_hi(bv.x); f.z = bf_lo(bv.y); f.w = bf_hi(bv.y);
            *(float4*)&Bs[srow * 32 + sseg] = f;
            f.x = bf_lo(bv.z); f.y = bf_hi(bv.z); f.z = bf_lo(bv.w); f.w = bf_hi(bv.w);
            *(float4*)&Bs[srow * 32 + sseg + 4] = f;
        }
        // stage W tiles [32][128]
#pragma unroll
        for (int t = 0; t < 4; t++) {
            int f = tid + t * 256;
            int k = f >> 5, j4 = (f & 31) * 4;
            *(float4*)&W1s[k * 128 + j4] = *(const float4*)&W1T[(size_t)(k0 + k) * 128 + j4];
            *(float4*)&W2s[k * 128 + j4] = *(const float4*)&W2T[(size_t)(k0 + k) * 128 + j4];
        }
        __syncthreads();

#pragma unroll
        for (int kk = 0; kk < 32; kk += 4) {
            const float4 w1a = *(const float4*)&W1s[(kk + 0) * 128 + j0];
            const float4 w1b = *(const float4*)&W1s[(kk + 1) * 128 + j0];
            const float4 w1c = *(const float4*)&W1s[(kk + 2) * 128 + j0];
            const float4 w1d = *(const float4*)&W1s[(kk + 3) * 128 + j0];
            const float4 w2a = *(const float4*)&W2s[(kk + 0) * 128 + j0];
            const float4 w2b = *(const float4*)&W2s[(kk + 1) * 128 + j0];
            const float4 w2c = *(const float4*)&W2s[(kk + 2) * 128 + j0];
            const float4 w2d = *(const float4*)&W2s[(kk + 3) * 128 + j0];
#pragma unroll
            for (int q = 0; q < 8; q++) {
                const int r = ty * 8 + q;
                const float4 a = *(const float4*)&As[r * 32 + kk];
                const float4 b = *(const float4*)&Bs[r * 32 + kk];
                FMA4(q, a.x, w1a)
                FMA4(q, a.y, w1b)
                FMA4(q, a.z, w1c)
                FMA4(q, a.w, w1d)
                FMA4(q, b.x, w2a)
                FMA4(q, b.y, w2b)
                FMA4(q, b.z, w2c)
                FMA4(q, b.w, w2d)
            }
        }
        __syncthreads();
    }

    const float4 bv4 = *(const float4*)&bias[j0];
#pragma unroll
    for (int q = 0; q < 8; q++) {
        int grow = r0 + ty * 8 + q;
        if (grow < n) {
            float4 o;
            o.x = acc[q].x + bv4.x;
            o.y = acc[q].y + bv4.y;
            o.z = acc[q].z + bv4.z;
            o.w = acc[q].w + bv4.w;
            if (relu) {
                o.x = fmaxf(o.x, 0.f);
                o.y = fmaxf(o.y, 0.f);
                o.z = fmaxf(o.z, 0.f);
                o.w = fmaxf(o.w, 0.f);
            }
            if (OUT_BF16) {
                u32 p0 = f2bf(o.x) | (f2bf(o.y) << 16);
                u32 p1 = f2bf(o.z) | (f2bf(o.w) << 16);
                *(uint2*)&OutB[(size_t)grow * 128 + j0] = make_uint2(p0, p1);
            } else {
                *(float4*)&OutF[(size_t)grow * ldo + j0] = o;
            }
        }
    }
}

extern "C" void kernel_launch(void* const* d_in, const int* in_sizes, int n_in,
                              void* d_out, int out_size, void* d_ws, size_t ws_size,
                              hipStream_t stream) {
    const float* x = (const float*)d_in[0];
    const int* src = (const int*)d_in[1];
    const int* dst = (const int*)d_in[2];
    const float* Wn0 = (const float*)d_in[3];
    const float* Ws0 = (const float*)d_in[4];
    const float* b0 = (const float*)d_in[5];
    const float* Wn1 = (const float*)d_in[6];
    const float* Ws1 = (const float*)d_in[7];
    const float* b1 = (const float*)d_in[8];

    const int N = in_sizes[0] / 64;
    const int E = in_sizes[1];
    float* out = (float*)d_out;

    // ---- workspace layout (~93 MB) ----
    char* w = (char*)d_ws;
    size_t o = 0;
    auto alloc = [&](size_t bytes) -> void* {
        o = (o + 255) & ~(size_t)255;
        void* p = w + o;
        o += bytes;
        return p;
    };
    int* deg_in = (int*)alloc((size_t)N * 4);
    int* deg_out = (int*)alloc((size_t)N * 4);
    int* off_in = (int*)alloc((size_t)(N + 1) * 4);
    int* off_out = (int*)alloc((size_t)(N + 1) * 4);
    int* cur_in = (int*)alloc((size_t)N * 4);
    int* cur_out = (int*)alloc((size_t)N * 4);
    int* excl = (int*)alloc((size_t)N * 4);
    int* bsums = (int*)alloc(1024 * 4);
    int* adj_in = (int*)alloc((size_t)E * 4);
    int* adj_out = (int*)alloc((size_t)E * 4);
    u16* AGGb = (u16*)alloc((size_t)N * 128 * 2);  // L1 agg; L0 uses as 2x[N][64]
    u16* h1b = (u16*)alloc((size_t)N * 128 * 2);
    u16* u1b = (u16*)alloc((size_t)N * 128 * 2);
    float* WsT0 = (float*)alloc(2 * 64 * 128 * 4);
    float* WnT0 = (float*)alloc(2 * 64 * 128 * 4);
    float* WsT1 = (float*)alloc(2 * 128 * 128 * 4);
    float* WnT1 = (float*)alloc(2 * 128 * 128 * 4);
    (void)ws_size;

    // xb (bf16 copy of x, [N][64]) lives in d_out scratch: dead before the
    // final L1 gemms write d_out.
    u16* xb = (u16*)d_out;

    const int nb1 = (N + 1023) / 1024;  // scan blocks (98) — must be <= 128

    // ---- weight pre-transpose + x conversion (independent of graph build) ----
    k_transpose<<<64, 256, 0, stream>>>(Ws0, WsT0, 128, 64, 2);
    k_transpose<<<64, 256, 0, stream>>>(Wn0, WnT0, 128, 64, 2);
    k_transpose<<<128, 256, 0, stream>>>(Ws1, WsT1, 128, 128, 2);
    k_transpose<<<128, 256, 0, stream>>>(Wn1, WnT1, 128, 128, 2);
    k_cvt_bf16<<<(N * 64 / 4 + 255) / 256, 256, 0, stream>>>(x, xb, N * 64 / 4);

    // ---- CSR build ----
    k_zero<<<(N + 255) / 256, 256, 0, stream>>>(deg_in, N);
    k_zero<<<(N + 255) / 256, 256, 0, stream>>>(deg_out, N);
    k_degrees<<<(E + 255) / 256, 256, 0, stream>>>(src, dst, deg_in, deg_out, E);

    k_scan1<<<nb1, 256, 0, stream>>>(deg_in, excl, bsums, N);
    k_scan2<<<1, 128, 0, stream>>>(bsums, nb1);
    k_scan3<<<(N + 255) / 256, 256, 0, stream>>>(excl, bsums, off_in, N, E);

    k_scan1<<<nb1, 256, 0, stream>>>(deg_out, excl, bsums, N);
    k_scan2<<<1, 128, 0, stream>>>(bsums, nb1);
    k_scan3<<<(N + 255) / 256, 256, 0, stream>>>(excl, bsums, off_out, N, E);

    k_copy2<<<(N + 255) / 256, 256, 0, stream>>>(off_in, cur_in, off_out, cur_out, N);
    k_scatter<<<(E + 255) / 256, 256, 0, stream>>>(src, dst, cur_in, cur_out, adj_in, adj_out, E);

    const int nodeBlocks = (N + 3) / 4;
    const int gemmBlocks = (N + 63) / 64;

    // ---- layer 0 ----
    u16* agg0b = AGGb;                    // [N][64]
    u16* aggUb = AGGb + (size_t)N * 64;   // [N][64]
    k_agg_l0_b<<<nodeBlocks, 256, 0, stream>>>(xb, off_in, adj_in, off_out, adj_out,
                                               agg0b, aggUb, N);
    k_gemm_dual_b<1><<<gemmBlocks, 256, 0, stream>>>(xb, 64, agg0b, 64, WsT0, WnT0, b0,
                                                     (float*)nullptr, 0, h1b, 64, N, 1);
    k_gemm_dual_b<1><<<gemmBlocks, 256, 0, stream>>>(xb, 64, aggUb, 64, WsT0 + 64 * 128,
                                                     WnT0 + 64 * 128, b0 + 128,
                                                     (float*)nullptr, 0, u1b, 64, N, 1);

    // ---- layer 1 ----
    // head0: 'I' -> aggregate h1 over out-edges
    k_agg_l1_b<<<nodeBlocks, 256, 0, stream>>>(h1b, off_out, adj_out, (const int*)nullptr,
                                               (const int*)nullptr, AGGb, N);
    k_gemm_dual_b<0><<<gemmBlocks, 256, 0, stream>>>(h1b, 128, AGGb, 128, WsT1, WnT1, b1,
                                                     out, 256, (u16*)nullptr, 128, N, 0);
    // head1: 'U' -> aggregate u1 over in+out edges
    k_agg_l1_b<<<nodeBlocks, 256, 0, stream>>>(u1b, off_in, adj_in, off_out, adj_out, AGGb, N);
    k_gemm_dual_b<0><<<gemmBlocks, 256, 0, stream>>>(u1b, 128, AGGb, 128, WsT1 + 128 * 128,
                                                     WnT1 + 128 * 128, b1 + 128,
                                                     out + 128, 256, (u16*)nullptr, 128, N, 0);
}

// Round 4
// 1059.799 us; speedup vs baseline: 8.4797x; 1.1562x over previous
//
#include <hip/hip_runtime.h>

// ---------------------------------------------------------------------------
// SAGEMultiSwitchModel: 2 heads x 2 SAGE layers on N=100k nodes, E=1.6M edges.
// head0 dirs "OI" (in-edges, then out-edges), head1 "UU" (undirected both).
// Layer: out = act([h | seg_mean(h)] @ [Ws|Wn]^T + b).
// R1: spill-free fp32 gemm (was 9 GB scratch traffic/dispatch).
// R2: bf16 side tables for gathered intermediates (halved gather traffic).
// R3: scatter/degrees x4-unrolled (4 independent atomics+stores per thread,
//     was 1 edge/thread latency-bound at 285us); launch fusion 23->14 kernels
//     (prep=cvt+transposes, dual-array scan, scan3+cur-copy); agg gathers x4.
// ---------------------------------------------------------------------------

typedef unsigned short u16;
typedef unsigned int u32;

__device__ __forceinline__ u32 f2bf(float f) {  // RNE float->bf16 (low 16 bits)
    u32 u = __float_as_uint(f);
    return (u + 0x7fffu + ((u >> 16) & 1u)) >> 16;
}
__device__ __forceinline__ float bf_lo(u32 v) { return __uint_as_float(v << 16); }
__device__ __forceinline__ float bf_hi(u32 v) { return __uint_as_float(v & 0xffff0000u); }

__global__ void k_zero(int* a, int n) {
    int i = blockIdx.x * blockDim.x + threadIdx.x;
    if (i < n) a[i] = 0;
}

// fused prep: x -> bf16 (n4 float4 groups), then 4 weight transposes
// L0 weights [2][128][64] -> [2][64][128]; L1 weights [2][128][128] -> same.
__global__ void k_prep(const float* __restrict__ x, u16* __restrict__ xb, int n4,
                       const float* __restrict__ Ws0, float* __restrict__ WsT0,
                       const float* __restrict__ Wn0, float* __restrict__ WnT0,
                       const float* __restrict__ Ws1, float* __restrict__ WsT1,
                       const float* __restrict__ Wn1, float* __restrict__ WnT1) {
    int i = blockIdx.x * blockDim.x + threadIdx.x;
    if (i < n4) {
        float4 v = *(const float4*)&x[(size_t)i * 4];
        u32 p0 = f2bf(v.x) | (f2bf(v.y) << 16);
        u32 p1 = f2bf(v.z) | (f2bf(v.w) << 16);
        *(uint2*)&xb[(size_t)i * 4] = make_uint2(p0, p1);
        return;
    }
    int t = i - n4;
    const float* s;
    float* d;
    int K;  // inner (source) dim
    if (t < 16384) { s = Ws0; d = WsT0; K = 64; }
    else if (t < 32768) { s = Wn0; d = WnT0; K = 64; t -= 16384; }
    else if (t < 65536) { s = Ws1; d = WsT1; K = 128; t -= 32768; }
    else if (t < 98304) { s = Wn1; d = WnT1; K = 128; t -= 65536; }
    else return;
    int h = t / (128 * K);
    int r = t - h * (128 * K);
    int j = r / K;
    int k = r - j * K;
    d[h * K * 128 + k * 128 + j] = s[t];
}

// x4-unrolled degree count: 8 independent atomics per thread
__global__ void k_degrees(const int* __restrict__ src, const int* __restrict__ dst,
                          int* deg_in, int* deg_out, int E) {
    int e0 = (blockIdx.x * blockDim.x + threadIdx.x) * 4;
    if (e0 + 3 < E) {
        int4 s = *(const int4*)&src[e0];
        int4 d = *(const int4*)&dst[e0];
        atomicAdd(&deg_in[d.x], 1);
        atomicAdd(&deg_in[d.y], 1);
        atomicAdd(&deg_in[d.z], 1);
        atomicAdd(&deg_in[d.w], 1);
        atomicAdd(&deg_out[s.x], 1);
        atomicAdd(&deg_out[s.y], 1);
        atomicAdd(&deg_out[s.z], 1);
        atomicAdd(&deg_out[s.w], 1);
    } else {
        for (int e = e0; e < E; e++) {
            atomicAdd(&deg_in[dst[e]], 1);
            atomicAdd(&deg_out[src[e]], 1);
        }
    }
}

// dual-array exclusive scan, 1024 elems/block; blocks [0,nb1) -> array0,
// [nb1,2nb1) -> array1. deg/excl are [2][n], bsums [2][1024].
__global__ void k_scan1(const int* __restrict__ deg, int* __restrict__ excl,
                        int* __restrict__ bsums, int n, int nb1) {
    __shared__ int ts[256];
    const int tid = threadIdx.x;
    const int arr = (blockIdx.x >= nb1) ? 1 : 0;
    const int blk = blockIdx.x - arr * nb1;
    const int* dg = deg + (size_t)arr * n;
    int* ex = excl + (size_t)arr * n;
    const int base = blk * 1024 + tid * 4;
    int p[4];
    int s = 0;
#pragma unroll
    for (int i = 0; i < 4; i++) {
        int v = (base + i < n) ? dg[base + i] : 0;
        p[i] = s;
        s += v;
    }
    ts[tid] = s;
    __syncthreads();
    for (int ofs = 1; ofs < 256; ofs <<= 1) {
        int t = (tid >= ofs) ? ts[tid - ofs] : 0;
        __syncthreads();
        ts[tid] += t;
        __syncthreads();
    }
    int texcl = ts[tid] - s;
#pragma unroll
    for (int i = 0; i < 4; i++)
        if (base + i < n) ex[base + i] = texcl + p[i];
    if (tid == 255) bsums[arr * 1024 + blk] = ts[255];
}

// block 0 -> bsums[0:1024], block 1 -> bsums[1024:2048]
__global__ void k_scan2(int* bsums, int nb) {
    __shared__ int ts[128];
    int* bs = bsums + blockIdx.x * 1024;
    const int tid = threadIdx.x;
    int v = (tid < nb) ? bs[tid] : 0;
    ts[tid] = v;
    __syncthreads();
    for (int ofs = 1; ofs < 128; ofs <<= 1) {
        int t = (tid >= ofs) ? ts[tid - ofs] : 0;
        __syncthreads();
        ts[tid] += t;
        __syncthreads();
    }
    if (tid < nb) bs[tid] = ts[tid] - v;  // exclusive
}

// finalize offsets for both arrays + copy into cur[2n]
__global__ void k_scan3(const int* __restrict__ excl, const int* __restrict__ bsums,
                        int* __restrict__ off_in, int* __restrict__ off_out,
                        int* __restrict__ cur, int n, int total) {
    int i = blockIdx.x * blockDim.x + threadIdx.x;
    if (i >= 2 * n) return;
    int arr = (i >= n) ? 1 : 0;
    int idx = i - arr * n;
    int v = excl[i] + bsums[arr * 1024 + (idx >> 10)];
    int* off = arr ? off_out : off_in;
    off[idx] = v;
    cur[i] = v;
    if (idx == 0) off[n] = total;
}

// x4-unrolled scatter: 8 independent atomics + 8 stores per thread
__global__ void k_scatter(const int* __restrict__ src, const int* __restrict__ dst,
                          int* cur_in, int* cur_out, int* adj_in, int* adj_out, int E) {
    int e0 = (blockIdx.x * blockDim.x + threadIdx.x) * 4;
    if (e0 + 3 < E) {
        int4 s = *(const int4*)&src[e0];
        int4 d = *(const int4*)&dst[e0];
        int p0 = atomicAdd(&cur_in[d.x], 1);
        int p1 = atomicAdd(&cur_in[d.y], 1);
        int p2 = atomicAdd(&cur_in[d.z], 1);
        int p3 = atomicAdd(&cur_in[d.w], 1);
        int q0 = atomicAdd(&cur_out[s.x], 1);
        int q1 = atomicAdd(&cur_out[s.y], 1);
        int q2 = atomicAdd(&cur_out[s.z], 1);
        int q3 = atomicAdd(&cur_out[s.w], 1);
        adj_in[p0] = s.x;
        adj_in[p1] = s.y;
        adj_in[p2] = s.z;
        adj_in[p3] = s.w;
        adj_out[q0] = d.x;
        adj_out[q1] = d.y;
        adj_out[q2] = d.z;
        adj_out[q3] = d.w;
    } else {
        for (int e = e0; e < E; e++) {
            int s = src[e], d = dst[e];
            adj_in[atomicAdd(&cur_in[d], 1)] = s;
            adj_out[atomicAdd(&cur_out[s], 1)] = d;
        }
    }
}

// layer-0 aggregation: F=64 bf16 gather, wave per node, x4 unrolled.
__global__ void __launch_bounds__(256) k_agg_l0_b(
        const u16* __restrict__ xb,
        const int* __restrict__ off_in, const int* __restrict__ adj_in,
        const int* __restrict__ off_out, const int* __restrict__ adj_out,
        u16* __restrict__ agg0b, u16* __restrict__ aggUb, int n) {
    const int node = blockIdx.x * 4 + (threadIdx.x >> 6);
    const int lane = threadIdx.x & 63;
    if (node >= n) return;
    const int a0 = off_in[node], a1 = off_in[node + 1];
    const int b0 = off_out[node], b1 = off_out[node + 1];
    float sin_ = 0.f, sout_ = 0.f;
    int j = a0;
    for (; j + 3 < a1; j += 4) {
        int i0 = adj_in[j], i1 = adj_in[j + 1], i2 = adj_in[j + 2], i3 = adj_in[j + 3];
        float v0 = bf_lo((u32)xb[(size_t)i0 * 64 + lane]);
        float v1 = bf_lo((u32)xb[(size_t)i1 * 64 + lane]);
        float v2 = bf_lo((u32)xb[(size_t)i2 * 64 + lane]);
        float v3 = bf_lo((u32)xb[(size_t)i3 * 64 + lane]);
        sin_ += (v0 + v1) + (v2 + v3);
    }
    for (; j < a1; j++) sin_ += bf_lo((u32)xb[(size_t)adj_in[j] * 64 + lane]);
    j = b0;
    for (; j + 3 < b1; j += 4) {
        int i0 = adj_out[j], i1 = adj_out[j + 1], i2 = adj_out[j + 2], i3 = adj_out[j + 3];
        float v0 = bf_lo((u32)xb[(size_t)i0 * 64 + lane]);
        float v1 = bf_lo((u32)xb[(size_t)i1 * 64 + lane]);
        float v2 = bf_lo((u32)xb[(size_t)i2 * 64 + lane]);
        float v3 = bf_lo((u32)xb[(size_t)i3 * 64 + lane]);
        sout_ += (v0 + v1) + (v2 + v3);
    }
    for (; j < b1; j++) sout_ += bf_lo((u32)xb[(size_t)adj_out[j] * 64 + lane]);
    const int din = a1 - a0, dout = b1 - b0;
    const int du = din + dout;
    agg0b[(size_t)node * 64 + lane] = (u16)f2bf(din ? sin_ / (float)din : 0.f);
    aggUb[(size_t)node * 64 + lane] = (u16)f2bf(du ? (sin_ + sout_) / (float)du : 0.f);
}

// layer-1 aggregation: F=128 bf16 gather (lane reads packed u32 pair), x4.
__global__ void __launch_bounds__(256) k_agg_l1_b(
        const u16* __restrict__ Hb,
        const int* __restrict__ offA, const int* __restrict__ adjA,
        const int* __restrict__ offB, const int* __restrict__ adjB,
        u16* __restrict__ outb, int n) {
    const int node = blockIdx.x * 4 + (threadIdx.x >> 6);
    const int lane = threadIdx.x & 63;
    if (node >= n) return;
    float s0 = 0.f, s1 = 0.f;
    const int a0 = offA[node], a1 = offA[node + 1];
    int j = a0;
    for (; j + 3 < a1; j += 4) {
        int i0 = adjA[j], i1 = adjA[j + 1], i2 = adjA[j + 2], i3 = adjA[j + 3];
        u32 v0 = *(const u32*)&Hb[(size_t)i0 * 128 + lane * 2];
        u32 v1 = *(const u32*)&Hb[(size_t)i1 * 128 + lane * 2];
        u32 v2 = *(const u32*)&Hb[(size_t)i2 * 128 + lane * 2];
        u32 v3 = *(const u32*)&Hb[(size_t)i3 * 128 + lane * 2];
        s0 += (bf_lo(v0) + bf_lo(v1)) + (bf_lo(v2) + bf_lo(v3));
        s1 += (bf_hi(v0) + bf_hi(v1)) + (bf_hi(v2) + bf_hi(v3));
    }
    for (; j < a1; j++) {
        u32 v = *(const u32*)&Hb[(size_t)adjA[j] * 128 + lane * 2];
        s0 += bf_lo(v);
        s1 += bf_hi(v);
    }
    int deg = a1 - a0;
    if (offB) {
        const int b0 = offB[node], b1 = offB[node + 1];
        j = b0;
        for (; j + 3 < b1; j += 4) {
            int i0 = adjB[j], i1 = adjB[j + 1], i2 = adjB[j + 2], i3 = adjB[j + 3];
            u32 v0 = *(const u32*)&Hb[(size_t)i0 * 128 + lane * 2];
            u32 v1 = *(const u32*)&Hb[(size_t)i1 * 128 + lane * 2];
            u32 v2 = *(const u32*)&Hb[(size_t)i2 * 128 + lane * 2];
            u32 v3 = *(const u32*)&Hb[(size_t)i3 * 128 + lane * 2];
            s0 += (bf_lo(v0) + bf_lo(v1)) + (bf_lo(v2) + bf_lo(v3));
            s1 += (bf_hi(v0) + bf_hi(v1)) + (bf_hi(v2) + bf_hi(v3));
        }
        for (; j < b1; j++) {
            u32 v = *(const u32*)&Hb[(size_t)adjB[j] * 128 + lane * 2];
            s0 += bf_lo(v);
            s1 += bf_hi(v);
        }
        deg += b1 - b0;
    }
    float inv = deg ? 1.f / (float)deg : 0.f;
    u32 p = f2bf(s0 * inv) | (f2bf(s1 * inv) << 16);
    *(u32*)&outb[(size_t)node * 128 + lane * 2] = p;
}

// Out[n, 0:128] = act(A[n,:K] @ W1T + B[n,:K] @ W2T + bias)
// A,B packed bf16 [*,K]; W1T/W2T fp32 [K][128]. BM=64, 256 thr, 8x4/thread.
#define FMA4(q, av, wv)        \
    acc[q].x += (av) * wv.x;   \
    acc[q].y += (av) * wv.y;   \
    acc[q].z += (av) * wv.z;   \
    acc[q].w += (av) * wv.w;

template <int OUT_BF16>
__global__ void __launch_bounds__(256) k_gemm_dual_b(
        const u16* __restrict__ A, int lda,
        const u16* __restrict__ B, int ldb,
        const float* __restrict__ W1T, const float* __restrict__ W2T,
        const float* __restrict__ bias,
        float* __restrict__ OutF, int ldo, u16* __restrict__ OutB,
        int K, int n, int relu) {
    __shared__ float As[64 * 32];
    __shared__ float Bs[64 * 32];
    __shared__ float W1s[32 * 128];
    __shared__ float W2s[32 * 128];
    const int tid = threadIdx.x;
    const int r0 = blockIdx.x * 64;
    const int tx = tid & 31, ty = tid >> 5;
    const int j0 = tx * 4;
    const int srow = tid >> 2, sseg = (tid & 3) * 8;

    float4 acc[8];
#pragma unroll
    for (int q = 0; q < 8; q++) acc[q] = make_float4(0.f, 0.f, 0.f, 0.f);

    for (int k0 = 0; k0 < K; k0 += 32) {
        {
            const int grow = r0 + srow;
            uint4 av = make_uint4(0, 0, 0, 0), bv = make_uint4(0, 0, 0, 0);
            if (grow < n) {
                av = *(const uint4*)&A[(size_t)grow * lda + k0 + sseg];
                bv = *(const uint4*)&B[(size_t)grow * ldb + k0 + sseg];
            }
            float4 f;
            f.x = bf_lo(av.x); f.y = bf_hi(av.x); f.z = bf_lo(av.y); f.w = bf_hi(av.y);
            *(float4*)&As[srow * 32 + sseg] = f;
            f.x = bf_lo(av.z); f.y = bf_hi(av.z); f.z = bf_lo(av.w); f.w = bf_hi(av.w);
            *(float4*)&As[srow * 32 + sseg + 4] = f;
            f.x = bf_lo(bv.x); f.y = bf_hi(bv.x); f.z = bf_lo(bv.y); f.w = bf_hi(bv.y);
            *(float4*)&Bs[srow * 32 + sseg] = f;
            f.x = bf_lo(bv.z); f.y = bf_hi(bv.z); f.z = bf_lo(bv.w); f.w = bf_hi(bv.w);
            *(float4*)&Bs[srow * 32 + sseg + 4] = f;
        }
#pragma unroll
        for (int t = 0; t < 4; t++) {
            int f = tid + t * 256;
            int k = f >> 5, j4 = (f & 31) * 4;
            *(float4*)&W1s[k * 128 + j4] = *(const float4*)&W1T[(size_t)(k0 + k) * 128 + j4];
            *(float4*)&W2s[k * 128 + j4] = *(const float4*)&W2T[(size_t)(k0 + k) * 128 + j4];
        }
        __syncthreads();

#pragma unroll
        for (int kk = 0; kk < 32; kk += 4) {
            const float4 w1a = *(const float4*)&W1s[(kk + 0) * 128 + j0];
            const float4 w1b = *(const float4*)&W1s[(kk + 1) * 128 + j0];
            const float4 w1c = *(const float4*)&W1s[(kk + 2) * 128 + j0];
            const float4 w1d = *(const float4*)&W1s[(kk + 3) * 128 + j0];
            const float4 w2a = *(const float4*)&W2s[(kk + 0) * 128 + j0];
            const float4 w2b = *(const float4*)&W2s[(kk + 1) * 128 + j0];
            const float4 w2c = *(const float4*)&W2s[(kk + 2) * 128 + j0];
            const float4 w2d = *(const float4*)&W2s[(kk + 3) * 128 + j0];
#pragma unroll
            for (int q = 0; q < 8; q++) {
                const int r = ty * 8 + q;
                const float4 a = *(const float4*)&As[r * 32 + kk];
                const float4 b = *(const float4*)&Bs[r * 32 + kk];
                FMA4(q, a.x, w1a)
                FMA4(q, a.y, w1b)
                FMA4(q, a.z, w1c)
                FMA4(q, a.w, w1d)
                FMA4(q, b.x, w2a)
                FMA4(q, b.y, w2b)
                FMA4(q, b.z, w2c)
                FMA4(q, b.w, w2d)
            }
        }
        __syncthreads();
    }

    const float4 bv4 = *(const float4*)&bias[j0];
#pragma unroll
    for (int q = 0; q < 8; q++) {
        int grow = r0 + ty * 8 + q;
        if (grow < n) {
            float4 o;
            o.x = acc[q].x + bv4.x;
            o.y = acc[q].y + bv4.y;
            o.z = acc[q].z + bv4.z;
            o.w = acc[q].w + bv4.w;
            if (relu) {
                o.x = fmaxf(o.x, 0.f);
                o.y = fmaxf(o.y, 0.f);
                o.z = fmaxf(o.z, 0.f);
                o.w = fmaxf(o.w, 0.f);
            }
            if (OUT_BF16) {
                u32 p0 = f2bf(o.x) | (f2bf(o.y) << 16);
                u32 p1 = f2bf(o.z) | (f2bf(o.w) << 16);
                *(uint2*)&OutB[(size_t)grow * 128 + j0] = make_uint2(p0, p1);
            } else {
                *(float4*)&OutF[(size_t)grow * ldo + j0] = o;
            }
        }
    }
}

extern "C" void kernel_launch(void* const* d_in, const int* in_sizes, int n_in,
                              void* d_out, int out_size, void* d_ws, size_t ws_size,
                              hipStream_t stream) {
    const float* x = (const float*)d_in[0];
    const int* src = (const int*)d_in[1];
    const int* dst = (const int*)d_in[2];
    const float* Wn0 = (const float*)d_in[3];
    const float* Ws0 = (const float*)d_in[4];
    const float* b0 = (const float*)d_in[5];
    const float* Wn1 = (const float*)d_in[6];
    const float* Ws1 = (const float*)d_in[7];
    const float* b1 = (const float*)d_in[8];

    const int N = in_sizes[0] / 64;
    const int E = in_sizes[1];
    float* out = (float*)d_out;

    // ---- workspace layout ----
    char* w = (char*)d_ws;
    size_t o = 0;
    auto alloc = [&](size_t bytes) -> void* {
        o = (o + 255) & ~(size_t)255;
        void* p = w + o;
        o += bytes;
        return p;
    };
    int* deg = (int*)alloc((size_t)2 * N * 4);   // [deg_in | deg_out]
    int* excl = (int*)alloc((size_t)2 * N * 4);
    int* cur = (int*)alloc((size_t)2 * N * 4);   // [cur_in | cur_out]
    int* off_in = (int*)alloc((size_t)(N + 1) * 4);
    int* off_out = (int*)alloc((size_t)(N + 1) * 4);
    int* bsums = (int*)alloc(2048 * 4);
    int* adj_in = (int*)alloc((size_t)E * 4);
    int* adj_out = (int*)alloc((size_t)E * 4);
    u16* AGGb = (u16*)alloc((size_t)N * 128 * 2);  // L1 agg; L0 uses as 2x[N][64]
    u16* h1b = (u16*)alloc((size_t)N * 128 * 2);
    u16* u1b = (u16*)alloc((size_t)N * 128 * 2);
    float* WsT0 = (float*)alloc(2 * 64 * 128 * 4);
    float* WnT0 = (float*)alloc(2 * 64 * 128 * 4);
    float* WsT1 = (float*)alloc(2 * 128 * 128 * 4);
    float* WnT1 = (float*)alloc(2 * 128 * 128 * 4);
    (void)ws_size;

    // xb (bf16 [N][64]) lives in d_out scratch (dead before final L1 writes)
    u16* xb = (u16*)d_out;

    const int nb1 = (N + 1023) / 1024;  // per-array scan blocks (98) <= 1024
    const int n4 = N * 64 / 4;

    // ---- fused prep: x->bf16 + 4 weight transposes ----
    k_prep<<<(n4 + 98304 + 255) / 256, 256, 0, stream>>>(x, xb, n4, Ws0, WsT0, Wn0, WnT0,
                                                         Ws1, WsT1, Wn1, WnT1);

    // ---- CSR build ----
    k_zero<<<(2 * N + 255) / 256, 256, 0, stream>>>(deg, 2 * N);
    k_degrees<<<((E + 3) / 4 + 255) / 256, 256, 0, stream>>>(src, dst, deg, deg + N, E);
    k_scan1<<<2 * nb1, 256, 0, stream>>>(deg, excl, bsums, N, nb1);
    k_scan2<<<2, 128, 0, stream>>>(bsums, nb1);
    k_scan3<<<(2 * N + 255) / 256, 256, 0, stream>>>(excl, bsums, off_in, off_out, cur, N, E);
    k_scatter<<<((E + 3) / 4 + 255) / 256, 256, 0, stream>>>(src, dst, cur, cur + N,
                                                             adj_in, adj_out, E);

    const int nodeBlocks = (N + 3) / 4;
    const int gemmBlocks = (N + 63) / 64;

    // ---- layer 0 ----
    u16* agg0b = AGGb;                    // [N][64]
    u16* aggUb = AGGb + (size_t)N * 64;   // [N][64]
    k_agg_l0_b<<<nodeBlocks, 256, 0, stream>>>(xb, off_in, adj_in, off_out, adj_out,
                                               agg0b, aggUb, N);
    k_gemm_dual_b<1><<<gemmBlocks, 256, 0, stream>>>(xb, 64, agg0b, 64, WsT0, WnT0, b0,
                                                     (float*)nullptr, 0, h1b, 64, N, 1);
    k_gemm_dual_b<1><<<gemmBlocks, 256, 0, stream>>>(xb, 64, aggUb, 64, WsT0 + 64 * 128,
                                                     WnT0 + 64 * 128, b0 + 128,
                                                     (float*)nullptr, 0, u1b, 64, N, 1);

    // ---- layer 1 ----
    // head0: 'I' -> aggregate h1 over out-edges
    k_agg_l1_b<<<nodeBlocks, 256, 0, stream>>>(h1b, off_out, adj_out, (const int*)nullptr,
                                               (const int*)nullptr, AGGb, N);
    k_gemm_dual_b<0><<<gemmBlocks, 256, 0, stream>>>(h1b, 128, AGGb, 128, WsT1, WnT1, b1,
                                                     out, 256, (u16*)nullptr, 128, N, 0);
    // head1: 'U' -> aggregate u1 over in+out edges
    k_agg_l1_b<<<nodeBlocks, 256, 0, stream>>>(u1b, off_in, adj_in, off_out, adj_out, AGGb, N);
    k_gemm_dual_b<0><<<gemmBlocks, 256, 0, stream>>>(u1b, 128, AGGb, 128, WsT1 + 128 * 128,
                                                     WnT1 + 128 * 128, b1 + 128,
                                                     out + 128, 256, (u16*)nullptr, 128, N, 0);
}

// Round 5
// 757.908 us; speedup vs baseline: 11.8573x; 1.3983x over previous
//
#include <hip/hip_runtime.h>

// ---------------------------------------------------------------------------
// SAGEMultiSwitchModel: 2 heads x 2 SAGE layers on N=100k nodes, E=1.6M edges.
// head0 dirs "OI" (in-edges, then out-edges), head1 "UU" (undirected both).
// Layer: out = act([h | seg_mean(h)] @ [Ws|Wn]^T + b).
// R1: spill-free fp32 gemm (was 9 GB scratch traffic/dispatch).
// R2: bf16 side tables for gathered intermediates (halved gather traffic).
// R3: x4-unrolled scatter (neutral: write-amplification-bound, not latency).
// R4: CSR build via bucketed counting sort (bucket = node>>8, 391 buckets).
//     Random 4B adjacency writes (203 MB HBM write-amp, 272us) replaced by
//     bucket-clustered writes (~13 MB). degrees/scans eliminated (off diffs).
// ---------------------------------------------------------------------------

typedef unsigned short u16;
typedef unsigned int u32;

__device__ __forceinline__ u32 f2bf(float f) {  // RNE float->bf16 (low 16 bits)
    u32 u = __float_as_uint(f);
    return (u + 0x7fffu + ((u >> 16) & 1u)) >> 16;
}
__device__ __forceinline__ float bf_lo(u32 v) { return __uint_as_float(v << 16); }
__device__ __forceinline__ float bf_hi(u32 v) { return __uint_as_float(v & 0xffff0000u); }

__global__ void k_zero(int* a, int n) {
    int i = blockIdx.x * blockDim.x + threadIdx.x;
    if (i < n) a[i] = 0;
}

// fused prep: x -> bf16 (n4 float4 groups), then 4 weight transposes
__global__ void k_prep(const float* __restrict__ x, u16* __restrict__ xb, int n4,
                       const float* __restrict__ Ws0, float* __restrict__ WsT0,
                       const float* __restrict__ Wn0, float* __restrict__ WnT0,
                       const float* __restrict__ Ws1, float* __restrict__ WsT1,
                       const float* __restrict__ Wn1, float* __restrict__ WnT1) {
    int i = blockIdx.x * blockDim.x + threadIdx.x;
    if (i < n4) {
        float4 v = *(const float4*)&x[(size_t)i * 4];
        u32 p0 = f2bf(v.x) | (f2bf(v.y) << 16);
        u32 p1 = f2bf(v.z) | (f2bf(v.w) << 16);
        *(uint2*)&xb[(size_t)i * 4] = make_uint2(p0, p1);
        return;
    }
    int t = i - n4;
    const float* s;
    float* d;
    int K;
    if (t < 16384) { s = Ws0; d = WsT0; K = 64; }
    else if (t < 32768) { s = Wn0; d = WnT0; K = 64; t -= 16384; }
    else if (t < 65536) { s = Ws1; d = WsT1; K = 128; t -= 32768; }
    else if (t < 98304) { s = Wn1; d = WnT1; K = 128; t -= 65536; }
    else return;
    int h = t / (128 * K);
    int r = t - h * (128 * K);
    int j = r / K;
    int k = r - j * K;
    d[h * K * 128 + k * 128 + j] = s[t];
}

// ---- bucketed CSR build: NPB=256 nodes/bucket, bucket = node>>8 ----

// Pass A: bucket counts via LDS histograms (8 edges/thread)
__global__ void __launch_bounds__(256) k_bincnt(
        const int* __restrict__ src, const int* __restrict__ dst,
        int* cntD, int* cntS, int E, int NB) {
    __shared__ int hD[512], hS[512];
    const int tid = threadIdx.x;
    for (int i = tid; i < NB; i += 256) { hD[i] = 0; hS[i] = 0; }
    __syncthreads();
    const int base = (blockIdx.x * 256 + tid) * 8;
#pragma unroll
    for (int i = 0; i < 8; i++) {
        if (base + i < E) {
            atomicAdd(&hD[dst[base + i] >> 8], 1);
            atomicAdd(&hS[src[base + i] >> 8], 1);
        }
    }
    __syncthreads();
    for (int i = tid; i < NB; i += 256) {
        if (hD[i]) atomicAdd(&cntD[i], hD[i]);
        if (hS[i]) atomicAdd(&cntS[i], hS[i]);
    }
}

// Pass B: single-block exclusive scan of both count arrays -> bases + cursors
__global__ void __launch_bounds__(512) k_binscan(
        const int* __restrict__ cntD, const int* __restrict__ cntS,
        int* bbaseD, int* bbaseS, int* curD, int* curS,
        int* off_in, int* off_out, int NB, int N, int E) {
    __shared__ int ts[512];
    const int tid = threadIdx.x;
    int v = (tid < NB) ? cntD[tid] : 0;
    ts[tid] = v;
    __syncthreads();
    for (int ofs = 1; ofs < 512; ofs <<= 1) {
        int t = (tid >= ofs) ? ts[tid - ofs] : 0;
        __syncthreads();
        ts[tid] += t;
        __syncthreads();
    }
    int ex = ts[tid] - v;
    if (tid < NB) { bbaseD[tid] = ex; curD[tid] = ex; }
    if (tid == NB - 1) bbaseD[NB] = ex + v;
    __syncthreads();
    v = (tid < NB) ? cntS[tid] : 0;
    ts[tid] = v;
    __syncthreads();
    for (int ofs = 1; ofs < 512; ofs <<= 1) {
        int t = (tid >= ofs) ? ts[tid - ofs] : 0;
        __syncthreads();
        ts[tid] += t;
        __syncthreads();
    }
    ex = ts[tid] - v;
    if (tid < NB) { bbaseS[tid] = ex; curS[tid] = ex; }
    if (tid == NB - 1) bbaseS[NB] = ex + v;
    if (tid == 0) { off_in[N] = E; off_out[N] = E; }
}

// Pass C: scatter packed pairs ((key&255)<<24 | payload) into bucket-ordered
// arrays. LDS ranks + one base-reservation atomic per bucket per block.
__global__ void __launch_bounds__(256) k_binscatter(
        const int* __restrict__ src, const int* __restrict__ dst,
        int* curD, int* curS, u32* __restrict__ pairsD, u32* __restrict__ pairsS,
        int E, int NB) {
    __shared__ int hD[512], hS[512], bD[512], bS[512];
    const int tid = threadIdx.x;
    for (int i = tid; i < NB; i += 256) { hD[i] = 0; hS[i] = 0; }
    __syncthreads();
    const int base = (blockIdx.x * 256 + tid) * 8;
    int sv[8], dv[8], rD[8], rS[8];
#pragma unroll
    for (int i = 0; i < 8; i++) {
        if (base + i < E) {
            sv[i] = src[base + i];
            dv[i] = dst[base + i];
            rD[i] = atomicAdd(&hD[dv[i] >> 8], 1);
            rS[i] = atomicAdd(&hS[sv[i] >> 8], 1);
        }
    }
    __syncthreads();
    for (int i = tid; i < NB; i += 256) {
        bD[i] = hD[i] ? atomicAdd(&curD[i], hD[i]) : 0;
        bS[i] = hS[i] ? atomicAdd(&curS[i], hS[i]) : 0;
    }
    __syncthreads();
#pragma unroll
    for (int i = 0; i < 8; i++) {
        if (base + i < E) {
            pairsD[bD[dv[i] >> 8] + rD[i]] = ((u32)(dv[i] & 255) << 24) | (u32)sv[i];
            pairsS[bS[sv[i] >> 8] + rS[i]] = ((u32)(sv[i] & 255) << 24) | (u32)dv[i];
        }
    }
}

// Pass D: per (bucket, direction): local histogram + scan -> off[] + adj[]
__global__ void __launch_bounds__(256) k_bucket_csr(
        const u32* __restrict__ pairsD, const u32* __restrict__ pairsS,
        const int* __restrict__ bbaseD, const int* __restrict__ bbaseS,
        int* __restrict__ off_in, int* __restrict__ adj_in,
        int* __restrict__ off_out, int* __restrict__ adj_out, int N) {
    __shared__ int cnt[256], cur[256], ts[256];
    const int b = blockIdx.x >> 1;
    const int arr = blockIdx.x & 1;
    const u32* pairs = arr ? pairsS : pairsD;
    const int* bbase = arr ? bbaseS : bbaseD;
    int* off = arr ? off_out : off_in;
    int* adj = arr ? adj_out : adj_in;
    const int e0 = bbase[b], e1 = bbase[b + 1];
    const int tid = threadIdx.x;
    cnt[tid] = 0;
    __syncthreads();
    for (int e = e0 + tid; e < e1; e += 256) atomicAdd(&cnt[pairs[e] >> 24], 1);
    __syncthreads();
    int v = cnt[tid];
    ts[tid] = v;
    __syncthreads();
    for (int ofs = 1; ofs < 256; ofs <<= 1) {
        int t = (tid >= ofs) ? ts[tid - ofs] : 0;
        __syncthreads();
        ts[tid] += t;
        __syncthreads();
    }
    const int ex = ts[tid] - v;
    const int n = b * 256 + tid;
    if (n < N) off[n] = e0 + ex;
    cur[tid] = e0 + ex;
    __syncthreads();
    for (int e = e0 + tid; e < e1; e += 256) {
        u32 p = pairs[e];
        int w = atomicAdd(&cur[p >> 24], 1);
        adj[w] = (int)(p & 0xFFFFFFu);
    }
}

// layer-0 aggregation: F=64 bf16 gather, wave per node, x4 unrolled.
__global__ void __launch_bounds__(256) k_agg_l0_b(
        const u16* __restrict__ xb,
        const int* __restrict__ off_in, const int* __restrict__ adj_in,
        const int* __restrict__ off_out, const int* __restrict__ adj_out,
        u16* __restrict__ agg0b, u16* __restrict__ aggUb, int n) {
    const int node = blockIdx.x * 4 + (threadIdx.x >> 6);
    const int lane = threadIdx.x & 63;
    if (node >= n) return;
    const int a0 = off_in[node], a1 = off_in[node + 1];
    const int b0 = off_out[node], b1 = off_out[node + 1];
    float sin_ = 0.f, sout_ = 0.f;
    int j = a0;
    for (; j + 3 < a1; j += 4) {
        int i0 = adj_in[j], i1 = adj_in[j + 1], i2 = adj_in[j + 2], i3 = adj_in[j + 3];
        float v0 = bf_lo((u32)xb[(size_t)i0 * 64 + lane]);
        float v1 = bf_lo((u32)xb[(size_t)i1 * 64 + lane]);
        float v2 = bf_lo((u32)xb[(size_t)i2 * 64 + lane]);
        float v3 = bf_lo((u32)xb[(size_t)i3 * 64 + lane]);
        sin_ += (v0 + v1) + (v2 + v3);
    }
    for (; j < a1; j++) sin_ += bf_lo((u32)xb[(size_t)adj_in[j] * 64 + lane]);
    j = b0;
    for (; j + 3 < b1; j += 4) {
        int i0 = adj_out[j], i1 = adj_out[j + 1], i2 = adj_out[j + 2], i3 = adj_out[j + 3];
        float v0 = bf_lo((u32)xb[(size_t)i0 * 64 + lane]);
        float v1 = bf_lo((u32)xb[(size_t)i1 * 64 + lane]);
        float v2 = bf_lo((u32)xb[(size_t)i2 * 64 + lane]);
        float v3 = bf_lo((u32)xb[(size_t)i3 * 64 + lane]);
        sout_ += (v0 + v1) + (v2 + v3);
    }
    for (; j < b1; j++) sout_ += bf_lo((u32)xb[(size_t)adj_out[j] * 64 + lane]);
    const int din = a1 - a0, dout = b1 - b0;
    const int du = din + dout;
    agg0b[(size_t)node * 64 + lane] = (u16)f2bf(din ? sin_ / (float)din : 0.f);
    aggUb[(size_t)node * 64 + lane] = (u16)f2bf(du ? (sin_ + sout_) / (float)du : 0.f);
}

// layer-1 aggregation: F=128 bf16 gather (lane reads packed u32 pair), x4.
__global__ void __launch_bounds__(256) k_agg_l1_b(
        const u16* __restrict__ Hb,
        const int* __restrict__ offA, const int* __restrict__ adjA,
        const int* __restrict__ offB, const int* __restrict__ adjB,
        u16* __restrict__ outb, int n) {
    const int node = blockIdx.x * 4 + (threadIdx.x >> 6);
    const int lane = threadIdx.x & 63;
    if (node >= n) return;
    float s0 = 0.f, s1 = 0.f;
    const int a0 = offA[node], a1 = offA[node + 1];
    int j = a0;
    for (; j + 3 < a1; j += 4) {
        int i0 = adjA[j], i1 = adjA[j + 1], i2 = adjA[j + 2], i3 = adjA[j + 3];
        u32 v0 = *(const u32*)&Hb[(size_t)i0 * 128 + lane * 2];
        u32 v1 = *(const u32*)&Hb[(size_t)i1 * 128 + lane * 2];
        u32 v2 = *(const u32*)&Hb[(size_t)i2 * 128 + lane * 2];
        u32 v3 = *(const u32*)&Hb[(size_t)i3 * 128 + lane * 2];
        s0 += (bf_lo(v0) + bf_lo(v1)) + (bf_lo(v2) + bf_lo(v3));
        s1 += (bf_hi(v0) + bf_hi(v1)) + (bf_hi(v2) + bf_hi(v3));
    }
    for (; j < a1; j++) {
        u32 v = *(const u32*)&Hb[(size_t)adjA[j] * 128 + lane * 2];
        s0 += bf_lo(v);
        s1 += bf_hi(v);
    }
    int deg = a1 - a0;
    if (offB) {
        const int b0 = offB[node], b1 = offB[node + 1];
        j = b0;
        for (; j + 3 < b1; j += 4) {
            int i0 = adjB[j], i1 = adjB[j + 1], i2 = adjB[j + 2], i3 = adjB[j + 3];
            u32 v0 = *(const u32*)&Hb[(size_t)i0 * 128 + lane * 2];
            u32 v1 = *(const u32*)&Hb[(size_t)i1 * 128 + lane * 2];
            u32 v2 = *(const u32*)&Hb[(size_t)i2 * 128 + lane * 2];
            u32 v3 = *(const u32*)&Hb[(size_t)i3 * 128 + lane * 2];
            s0 += (bf_lo(v0) + bf_lo(v1)) + (bf_lo(v2) + bf_lo(v3));
            s1 += (bf_hi(v0) + bf_hi(v1)) + (bf_hi(v2) + bf_hi(v3));
        }
        for (; j < b1; j++) {
            u32 v = *(const u32*)&Hb[(size_t)adjB[j] * 128 + lane * 2];
            s0 += bf_lo(v);
            s1 += bf_hi(v);
        }
        deg += b1 - b0;
    }
    float inv = deg ? 1.f / (float)deg : 0.f;
    u32 p = f2bf(s0 * inv) | (f2bf(s1 * inv) << 16);
    *(u32*)&outb[(size_t)node * 128 + lane * 2] = p;
}

// Out[n, 0:128] = act(A[n,:K] @ W1T + B[n,:K] @ W2T + bias)
#define FMA4(q, av, wv)        \
    acc[q].x += (av) * wv.x;   \
    acc[q].y += (av) * wv.y;   \
    acc[q].z += (av) * wv.z;   \
    acc[q].w += (av) * wv.w;

template <int OUT_BF16>
__global__ void __launch_bounds__(256) k_gemm_dual_b(
        const u16* __restrict__ A, int lda,
        const u16* __restrict__ B, int ldb,
        const float* __restrict__ W1T, const float* __restrict__ W2T,
        const float* __restrict__ bias,
        float* __restrict__ OutF, int ldo, u16* __restrict__ OutB,
        int K, int n, int relu) {
    __shared__ float As[64 * 32];
    __shared__ float Bs[64 * 32];
    __shared__ float W1s[32 * 128];
    __shared__ float W2s[32 * 128];
    const int tid = threadIdx.x;
    const int r0 = blockIdx.x * 64;
    const int tx = tid & 31, ty = tid >> 5;
    const int j0 = tx * 4;
    const int srow = tid >> 2, sseg = (tid & 3) * 8;

    float4 acc[8];
#pragma unroll
    for (int q = 0; q < 8; q++) acc[q] = make_float4(0.f, 0.f, 0.f, 0.f);

    for (int k0 = 0; k0 < K; k0 += 32) {
        {
            const int grow = r0 + srow;
            uint4 av = make_uint4(0, 0, 0, 0), bv = make_uint4(0, 0, 0, 0);
            if (grow < n) {
                av = *(const uint4*)&A[(size_t)grow * lda + k0 + sseg];
                bv = *(const uint4*)&B[(size_t)grow * ldb + k0 + sseg];
            }
            float4 f;
            f.x = bf_lo(av.x); f.y = bf_hi(av.x); f.z = bf_lo(av.y); f.w = bf_hi(av.y);
            *(float4*)&As[srow * 32 + sseg] = f;
            f.x = bf_lo(av.z); f.y = bf_hi(av.z); f.z = bf_lo(av.w); f.w = bf_hi(av.w);
            *(float4*)&As[srow * 32 + sseg + 4] = f;
            f.x = bf_lo(bv.x); f.y = bf_hi(bv.x); f.z = bf_lo(bv.y); f.w = bf_hi(bv.y);
            *(float4*)&Bs[srow * 32 + sseg] = f;
            f.x = bf_lo(bv.z); f.y = bf_hi(bv.z); f.z = bf_lo(bv.w); f.w = bf_hi(bv.w);
            *(float4*)&Bs[srow * 32 + sseg + 4] = f;
        }
#pragma unroll
        for (int t = 0; t < 4; t++) {
            int f = tid + t * 256;
            int k = f >> 5, j4 = (f & 31) * 4;
            *(float4*)&W1s[k * 128 + j4] = *(const float4*)&W1T[(size_t)(k0 + k) * 128 + j4];
            *(float4*)&W2s[k * 128 + j4] = *(const float4*)&W2T[(size_t)(k0 + k) * 128 + j4];
        }
        __syncthreads();

#pragma unroll
        for (int kk = 0; kk < 32; kk += 4) {
            const float4 w1a = *(const float4*)&W1s[(kk + 0) * 128 + j0];
            const float4 w1b = *(const float4*)&W1s[(kk + 1) * 128 + j0];
            const float4 w1c = *(const float4*)&W1s[(kk + 2) * 128 + j0];
            const float4 w1d = *(const float4*)&W1s[(kk + 3) * 128 + j0];
            const float4 w2a = *(const float4*)&W2s[(kk + 0) * 128 + j0];
            const float4 w2b = *(const float4*)&W2s[(kk + 1) * 128 + j0];
            const float4 w2c = *(const float4*)&W2s[(kk + 2) * 128 + j0];
            const float4 w2d = *(const float4*)&W2s[(kk + 3) * 128 + j0];
#pragma unroll
            for (int q = 0; q < 8; q++) {
                const int r = ty * 8 + q;
                const float4 a = *(const float4*)&As[r * 32 + kk];
                const float4 b = *(const float4*)&Bs[r * 32 + kk];
                FMA4(q, a.x, w1a)
                FMA4(q, a.y, w1b)
                FMA4(q, a.z, w1c)
                FMA4(q, a.w, w1d)
                FMA4(q, b.x, w2a)
                FMA4(q, b.y, w2b)
                FMA4(q, b.z, w2c)
                FMA4(q, b.w, w2d)
            }
        }
        __syncthreads();
    }

    const float4 bv4 = *(const float4*)&bias[j0];
#pragma unroll
    for (int q = 0; q < 8; q++) {
        int grow = r0 + ty * 8 + q;
        if (grow < n) {
            float4 o;
            o.x = acc[q].x + bv4.x;
            o.y = acc[q].y + bv4.y;
            o.z = acc[q].z + bv4.z;
            o.w = acc[q].w + bv4.w;
            if (relu) {
                o.x = fmaxf(o.x, 0.f);
                o.y = fmaxf(o.y, 0.f);
                o.z = fmaxf(o.z, 0.f);
                o.w = fmaxf(o.w, 0.f);
            }
            if (OUT_BF16) {
                u32 p0 = f2bf(o.x) | (f2bf(o.y) << 16);
                u32 p1 = f2bf(o.z) | (f2bf(o.w) << 16);
                *(uint2*)&OutB[(size_t)grow * 128 + j0] = make_uint2(p0, p1);
            } else {
                *(float4*)&OutF[(size_t)grow * ldo + j0] = o;
            }
        }
    }
}

extern "C" void kernel_launch(void* const* d_in, const int* in_sizes, int n_in,
                              void* d_out, int out_size, void* d_ws, size_t ws_size,
                              hipStream_t stream) {
    const float* x = (const float*)d_in[0];
    const int* src = (const int*)d_in[1];
    const int* dst = (const int*)d_in[2];
    const float* Wn0 = (const float*)d_in[3];
    const float* Ws0 = (const float*)d_in[4];
    const float* b0 = (const float*)d_in[5];
    const float* Wn1 = (const float*)d_in[6];
    const float* Ws1 = (const float*)d_in[7];
    const float* b1 = (const float*)d_in[8];

    const int N = in_sizes[0] / 64;
    const int E = in_sizes[1];
    float* out = (float*)d_out;
    const int NB = (N + 255) >> 8;  // buckets of 256 nodes (391; must be <= 512)

    // ---- workspace layout ----
    char* w = (char*)d_ws;
    size_t o = 0;
    auto alloc = [&](size_t bytes) -> void* {
        o = (o + 255) & ~(size_t)255;
        void* p = w + o;
        o += bytes;
        return p;
    };
    int* off_in = (int*)alloc((size_t)(N + 1) * 4);
    int* off_out = (int*)alloc((size_t)(N + 1) * 4);
    int* cntD = (int*)alloc(512 * 4);
    int* cntS = (int*)alloc(512 * 4);
    int* curD = (int*)alloc(512 * 4);
    int* curS = (int*)alloc(512 * 4);
    int* bbaseD = (int*)alloc(513 * 4);
    int* bbaseS = (int*)alloc(513 * 4);
    int* adj_in = (int*)alloc((size_t)E * 4);
    int* adj_out = (int*)alloc((size_t)E * 4);
    u16* AGGb = (u16*)alloc((size_t)N * 128 * 2);  // L1 agg; L0 uses as 2x[N][64]
    u16* h1b = (u16*)alloc((size_t)N * 128 * 2);
    u16* u1b = (u16*)alloc((size_t)N * 128 * 2);
    float* WsT0 = (float*)alloc(2 * 64 * 128 * 4);
    float* WnT0 = (float*)alloc(2 * 64 * 128 * 4);
    float* WsT1 = (float*)alloc(2 * 128 * 128 * 4);
    float* WnT1 = (float*)alloc(2 * 128 * 128 * 4);
    (void)ws_size;

    // pair arrays alias h1b/u1b (dead until the L0 gemms run, after pass D)
    u32* pairsD = (u32*)h1b;
    u32* pairsS = (u32*)u1b;
    // xb (bf16 [N][64]) lives in d_out scratch (dead before final L1 writes)
    u16* xb = (u16*)d_out;

    const int n4 = N * 64 / 4;
    const int edgeBlocks = ((E + 7) / 8 + 255) / 256;

    // ---- fused prep: x->bf16 + 4 weight transposes ----
    k_prep<<<(n4 + 98304 + 255) / 256, 256, 0, stream>>>(x, xb, n4, Ws0, WsT0, Wn0, WnT0,
                                                         Ws1, WsT1, Wn1, WnT1);

    // ---- CSR build via bucketed counting sort ----
    k_zero<<<(1024 + 255) / 256, 256, 0, stream>>>(cntD, 1024);  // cntD+cntS contiguous
    k_bincnt<<<edgeBlocks, 256, 0, stream>>>(src, dst, cntD, cntS, E, NB);
    k_binscan<<<1, 512, 0, stream>>>(cntD, cntS, bbaseD, bbaseS, curD, curS,
                                     off_in, off_out, NB, N, E);
    k_binscatter<<<edgeBlocks, 256, 0, stream>>>(src, dst, curD, curS, pairsD, pairsS, E, NB);
    k_bucket_csr<<<2 * NB, 256, 0, stream>>>(pairsD, pairsS, bbaseD, bbaseS,
                                             off_in, adj_in, off_out, adj_out, N);

    const int nodeBlocks = (N + 3) / 4;
    const int gemmBlocks = (N + 63) / 64;

    // ---- layer 0 ----
    u16* agg0b = AGGb;                    // [N][64]
    u16* aggUb = AGGb + (size_t)N * 64;   // [N][64]
    k_agg_l0_b<<<nodeBlocks, 256, 0, stream>>>(xb, off_in, adj_in, off_out, adj_out,
                                               agg0b, aggUb, N);
    k_gemm_dual_b<1><<<gemmBlocks, 256, 0, stream>>>(xb, 64, agg0b, 64, WsT0, WnT0, b0,
                                                     (float*)nullptr, 0, h1b, 64, N, 1);
    k_gemm_dual_b<1><<<gemmBlocks, 256, 0, stream>>>(xb, 64, aggUb, 64, WsT0 + 64 * 128,
                                                     WnT0 + 64 * 128, b0 + 128,
                                                     (float*)nullptr, 0, u1b, 64, N, 1);

    // ---- layer 1 ----
    // head0: 'I' -> aggregate h1 over out-edges
    k_agg_l1_b<<<nodeBlocks, 256, 0, stream>>>(h1b, off_out, adj_out, (const int*)nullptr,
                                               (const int*)nullptr, AGGb, N);
    k_gemm_dual_b<0><<<gemmBlocks, 256, 0, stream>>>(h1b, 128, AGGb, 128, WsT1, WnT1, b1,
                                                     out, 256, (u16*)nullptr, 128, N, 0);
    // head1: 'U' -> aggregate u1 over in+out edges
    k_agg_l1_b<<<nodeBlocks, 256, 0, stream>>>(u1b, off_in, adj_in, off_out, adj_out, AGGb, N);
    k_gemm_dual_b<0><<<gemmBlocks, 256, 0, stream>>>(u1b, 128, AGGb, 128, WsT1 + 128 * 128,
                                                     WnT1 + 128 * 128, b1 + 128,
                                                     out + 128, 256, (u16*)nullptr, 128, N, 0);
}

// Round 6
// 622.730 us; speedup vs baseline: 14.4312x; 1.2171x over previous
//
#include <hip/hip_runtime.h>

// ---------------------------------------------------------------------------
// SAGEMultiSwitchModel: 2 heads x 2 SAGE layers on N=100k nodes, E=1.6M edges.
// head0 dirs "OI" (in-edges, then out-edges), head1 "UU" (undirected both).
// Layer: out = act([h | seg_mean(h)] @ [Ws|Wn]^T + b).
// R1: spill-free fp32 gemm. R2: bf16 side tables (halved gather traffic).
// R4: bucketed-counting-sort CSR build (write-amp fix, 1060->758us).
// R5: MFMA gemms (bf16 operands already in place; A-frags in regs, B-frags
//     read directly from untransposed bf16 weights; fp32 accum). VALU gemms
//     were ~200-250us combined at 128 FMA/cy/CU. Agg gathers x8-unrolled.
// Gather plateau note: random 256B-row gathers run at ~2.7 TB/s (R2 fp32 and
// R4 bf16 both) — agg kernels are near that pattern's ceiling.
// ---------------------------------------------------------------------------

typedef unsigned short u16;
typedef unsigned int u32;
typedef __bf16 bf16x8 __attribute__((ext_vector_type(8)));
typedef float f32x4 __attribute__((ext_vector_type(4)));

__device__ __forceinline__ u32 f2bf(float f) {  // RNE float->bf16 (low 16 bits)
    u32 u = __float_as_uint(f);
    return (u + 0x7fffu + ((u >> 16) & 1u)) >> 16;
}
__device__ __forceinline__ float bf_lo(u32 v) { return __uint_as_float(v << 16); }
__device__ __forceinline__ float bf_hi(u32 v) { return __uint_as_float(v & 0xffff0000u); }

__global__ void k_zero(int* a, int n) {
    int i = blockIdx.x * blockDim.x + threadIdx.x;
    if (i < n) a[i] = 0;
}

// fused prep: x -> bf16 (n4 float4 groups) + 4 weight tensors -> bf16 (flat)
__global__ void k_prep(const float* __restrict__ x, u16* __restrict__ xb, int n4,
                       const float* __restrict__ Ws0, const float* __restrict__ Wn0,
                       const float* __restrict__ Ws1, const float* __restrict__ Wn1,
                       u16* __restrict__ Wsb0, u16* __restrict__ Wnb0,
                       u16* __restrict__ Wsb1, u16* __restrict__ Wnb1) {
    int i = blockIdx.x * blockDim.x + threadIdx.x;
    if (i < n4) {
        float4 v = *(const float4*)&x[(size_t)i * 4];
        u32 p0 = f2bf(v.x) | (f2bf(v.y) << 16);
        u32 p1 = f2bf(v.z) | (f2bf(v.w) << 16);
        *(uint2*)&xb[(size_t)i * 4] = make_uint2(p0, p1);
        return;
    }
    int t = i - n4;
    if (t < 16384) Wsb0[t] = (u16)f2bf(Ws0[t]);
    else if (t < 32768) Wnb0[t - 16384] = (u16)f2bf(Wn0[t - 16384]);
    else if (t < 65536) Wsb1[t - 32768] = (u16)f2bf(Ws1[t - 32768]);
    else if (t < 98304) Wnb1[t - 65536] = (u16)f2bf(Wn1[t - 65536]);
}

// ---- bucketed CSR build: NPB=256 nodes/bucket, bucket = node>>8 ----

__global__ void __launch_bounds__(256) k_bincnt(
        const int* __restrict__ src, const int* __restrict__ dst,
        int* cntD, int* cntS, int E, int NB) {
    __shared__ int hD[512], hS[512];
    const int tid = threadIdx.x;
    for (int i = tid; i < NB; i += 256) { hD[i] = 0; hS[i] = 0; }
    __syncthreads();
    const int base = (blockIdx.x * 256 + tid) * 8;
#pragma unroll
    for (int i = 0; i < 8; i++) {
        if (base + i < E) {
            atomicAdd(&hD[dst[base + i] >> 8], 1);
            atomicAdd(&hS[src[base + i] >> 8], 1);
        }
    }
    __syncthreads();
    for (int i = tid; i < NB; i += 256) {
        if (hD[i]) atomicAdd(&cntD[i], hD[i]);
        if (hS[i]) atomicAdd(&cntS[i], hS[i]);
    }
}

__global__ void __launch_bounds__(512) k_binscan(
        const int* __restrict__ cntD, const int* __restrict__ cntS,
        int* bbaseD, int* bbaseS, int* curD, int* curS,
        int* off_in, int* off_out, int NB, int N, int E) {
    __shared__ int ts[512];
    const int tid = threadIdx.x;
    int v = (tid < NB) ? cntD[tid] : 0;
    ts[tid] = v;
    __syncthreads();
    for (int ofs = 1; ofs < 512; ofs <<= 1) {
        int t = (tid >= ofs) ? ts[tid - ofs] : 0;
        __syncthreads();
        ts[tid] += t;
        __syncthreads();
    }
    int ex = ts[tid] - v;
    if (tid < NB) { bbaseD[tid] = ex; curD[tid] = ex; }
    if (tid == NB - 1) bbaseD[NB] = ex + v;
    __syncthreads();
    v = (tid < NB) ? cntS[tid] : 0;
    ts[tid] = v;
    __syncthreads();
    for (int ofs = 1; ofs < 512; ofs <<= 1) {
        int t = (tid >= ofs) ? ts[tid - ofs] : 0;
        __syncthreads();
        ts[tid] += t;
        __syncthreads();
    }
    ex = ts[tid] - v;
    if (tid < NB) { bbaseS[tid] = ex; curS[tid] = ex; }
    if (tid == NB - 1) bbaseS[NB] = ex + v;
    if (tid == 0) { off_in[N] = E; off_out[N] = E; }
}

__global__ void __launch_bounds__(256) k_binscatter(
        const int* __restrict__ src, const int* __restrict__ dst,
        int* curD, int* curS, u32* __restrict__ pairsD, u32* __restrict__ pairsS,
        int E, int NB) {
    __shared__ int hD[512], hS[512], bD[512], bS[512];
    const int tid = threadIdx.x;
    for (int i = tid; i < NB; i += 256) { hD[i] = 0; hS[i] = 0; }
    __syncthreads();
    const int base = (blockIdx.x * 256 + tid) * 8;
    int sv[8], dv[8], rD[8], rS[8];
#pragma unroll
    for (int i = 0; i < 8; i++) {
        if (base + i < E) {
            sv[i] = src[base + i];
            dv[i] = dst[base + i];
            rD[i] = atomicAdd(&hD[dv[i] >> 8], 1);
            rS[i] = atomicAdd(&hS[sv[i] >> 8], 1);
        }
    }
    __syncthreads();
    for (int i = tid; i < NB; i += 256) {
        bD[i] = hD[i] ? atomicAdd(&curD[i], hD[i]) : 0;
        bS[i] = hS[i] ? atomicAdd(&curS[i], hS[i]) : 0;
    }
    __syncthreads();
#pragma unroll
    for (int i = 0; i < 8; i++) {
        if (base + i < E) {
            pairsD[bD[dv[i] >> 8] + rD[i]] = ((u32)(dv[i] & 255) << 24) | (u32)sv[i];
            pairsS[bS[sv[i] >> 8] + rS[i]] = ((u32)(sv[i] & 255) << 24) | (u32)dv[i];
        }
    }
}

__global__ void __launch_bounds__(256) k_bucket_csr(
        const u32* __restrict__ pairsD, const u32* __restrict__ pairsS,
        const int* __restrict__ bbaseD, const int* __restrict__ bbaseS,
        int* __restrict__ off_in, int* __restrict__ adj_in,
        int* __restrict__ off_out, int* __restrict__ adj_out, int N) {
    __shared__ int cnt[256], cur[256], ts[256];
    const int b = blockIdx.x >> 1;
    const int arr = blockIdx.x & 1;
    const u32* pairs = arr ? pairsS : pairsD;
    const int* bbase = arr ? bbaseS : bbaseD;
    int* off = arr ? off_out : off_in;
    int* adj = arr ? adj_out : adj_in;
    const int e0 = bbase[b], e1 = bbase[b + 1];
    const int tid = threadIdx.x;
    cnt[tid] = 0;
    __syncthreads();
    for (int e = e0 + tid; e < e1; e += 256) atomicAdd(&cnt[pairs[e] >> 24], 1);
    __syncthreads();
    int v = cnt[tid];
    ts[tid] = v;
    __syncthreads();
    for (int ofs = 1; ofs < 256; ofs <<= 1) {
        int t = (tid >= ofs) ? ts[tid - ofs] : 0;
        __syncthreads();
        ts[tid] += t;
        __syncthreads();
    }
    const int ex = ts[tid] - v;
    const int n = b * 256 + tid;
    if (n < N) off[n] = e0 + ex;
    cur[tid] = e0 + ex;
    __syncthreads();
    for (int e = e0 + tid; e < e1; e += 256) {
        u32 p = pairs[e];
        int w = atomicAdd(&cur[p >> 24], 1);
        adj[w] = (int)(p & 0xFFFFFFu);
    }
}

// layer-0 aggregation: F=64 bf16 gather, wave per node, x8 unrolled.
__global__ void __launch_bounds__(256) k_agg_l0_b(
        const u16* __restrict__ xb,
        const int* __restrict__ off_in, const int* __restrict__ adj_in,
        const int* __restrict__ off_out, const int* __restrict__ adj_out,
        u16* __restrict__ agg0b, u16* __restrict__ aggUb, int n) {
    const int node = blockIdx.x * 4 + (threadIdx.x >> 6);
    const int lane = threadIdx.x & 63;
    if (node >= n) return;
    const int a0 = off_in[node], a1 = off_in[node + 1];
    const int b0 = off_out[node], b1 = off_out[node + 1];
    float sin_ = 0.f, sout_ = 0.f;
    int j = a0;
    for (; j + 7 < a1; j += 8) {
        int i0 = adj_in[j], i1 = adj_in[j + 1], i2 = adj_in[j + 2], i3 = adj_in[j + 3];
        int i4 = adj_in[j + 4], i5 = adj_in[j + 5], i6 = adj_in[j + 6], i7 = adj_in[j + 7];
        float v0 = bf_lo((u32)xb[(size_t)i0 * 64 + lane]);
        float v1 = bf_lo((u32)xb[(size_t)i1 * 64 + lane]);
        float v2 = bf_lo((u32)xb[(size_t)i2 * 64 + lane]);
        float v3 = bf_lo((u32)xb[(size_t)i3 * 64 + lane]);
        float v4 = bf_lo((u32)xb[(size_t)i4 * 64 + lane]);
        float v5 = bf_lo((u32)xb[(size_t)i5 * 64 + lane]);
        float v6 = bf_lo((u32)xb[(size_t)i6 * 64 + lane]);
        float v7 = bf_lo((u32)xb[(size_t)i7 * 64 + lane]);
        sin_ += ((v0 + v1) + (v2 + v3)) + ((v4 + v5) + (v6 + v7));
    }
    for (; j < a1; j++) sin_ += bf_lo((u32)xb[(size_t)adj_in[j] * 64 + lane]);
    j = b0;
    for (; j + 7 < b1; j += 8) {
        int i0 = adj_out[j], i1 = adj_out[j + 1], i2 = adj_out[j + 2], i3 = adj_out[j + 3];
        int i4 = adj_out[j + 4], i5 = adj_out[j + 5], i6 = adj_out[j + 6], i7 = adj_out[j + 7];
        float v0 = bf_lo((u32)xb[(size_t)i0 * 64 + lane]);
        float v1 = bf_lo((u32)xb[(size_t)i1 * 64 + lane]);
        float v2 = bf_lo((u32)xb[(size_t)i2 * 64 + lane]);
        float v3 = bf_lo((u32)xb[(size_t)i3 * 64 + lane]);
        float v4 = bf_lo((u32)xb[(size_t)i4 * 64 + lane]);
        float v5 = bf_lo((u32)xb[(size_t)i5 * 64 + lane]);
        float v6 = bf_lo((u32)xb[(size_t)i6 * 64 + lane]);
        float v7 = bf_lo((u32)xb[(size_t)i7 * 64 + lane]);
        sout_ += ((v0 + v1) + (v2 + v3)) + ((v4 + v5) + (v6 + v7));
    }
    for (; j < b1; j++) sout_ += bf_lo((u32)xb[(size_t)adj_out[j] * 64 + lane]);
    const int din = a1 - a0, dout = b1 - b0;
    const int du = din + dout;
    agg0b[(size_t)node * 64 + lane] = (u16)f2bf(din ? sin_ / (float)din : 0.f);
    aggUb[(size_t)node * 64 + lane] = (u16)f2bf(du ? (sin_ + sout_) / (float)du : 0.f);
}

// layer-1 aggregation: F=128 bf16 gather (lane reads packed u32 pair), x8.
__global__ void __launch_bounds__(256) k_agg_l1_b(
        const u16* __restrict__ Hb,
        const int* __restrict__ offA, const int* __restrict__ adjA,
        const int* __restrict__ offB, const int* __restrict__ adjB,
        u16* __restrict__ outb, int n) {
    const int node = blockIdx.x * 4 + (threadIdx.x >> 6);
    const int lane = threadIdx.x & 63;
    if (node >= n) return;
    float s0 = 0.f, s1 = 0.f;
    const int a0 = offA[node], a1 = offA[node + 1];
    int j = a0;
    for (; j + 7 < a1; j += 8) {
        int i0 = adjA[j], i1 = adjA[j + 1], i2 = adjA[j + 2], i3 = adjA[j + 3];
        int i4 = adjA[j + 4], i5 = adjA[j + 5], i6 = adjA[j + 6], i7 = adjA[j + 7];
        u32 v0 = *(const u32*)&Hb[(size_t)i0 * 128 + lane * 2];
        u32 v1 = *(const u32*)&Hb[(size_t)i1 * 128 + lane * 2];
        u32 v2 = *(const u32*)&Hb[(size_t)i2 * 128 + lane * 2];
        u32 v3 = *(const u32*)&Hb[(size_t)i3 * 128 + lane * 2];
        u32 v4 = *(const u32*)&Hb[(size_t)i4 * 128 + lane * 2];
        u32 v5 = *(const u32*)&Hb[(size_t)i5 * 128 + lane * 2];
        u32 v6 = *(const u32*)&Hb[(size_t)i6 * 128 + lane * 2];
        u32 v7 = *(const u32*)&Hb[(size_t)i7 * 128 + lane * 2];
        s0 += ((bf_lo(v0) + bf_lo(v1)) + (bf_lo(v2) + bf_lo(v3))) +
              ((bf_lo(v4) + bf_lo(v5)) + (bf_lo(v6) + bf_lo(v7)));
        s1 += ((bf_hi(v0) + bf_hi(v1)) + (bf_hi(v2) + bf_hi(v3))) +
              ((bf_hi(v4) + bf_hi(v5)) + (bf_hi(v6) + bf_hi(v7)));
    }
    for (; j < a1; j++) {
        u32 v = *(const u32*)&Hb[(size_t)adjA[j] * 128 + lane * 2];
        s0 += bf_lo(v);
        s1 += bf_hi(v);
    }
    int deg = a1 - a0;
    if (offB) {
        const int b0 = offB[node], b1 = offB[node + 1];
        j = b0;
        for (; j + 7 < b1; j += 8) {
            int i0 = adjB[j], i1 = adjB[j + 1], i2 = adjB[j + 2], i3 = adjB[j + 3];
            int i4 = adjB[j + 4], i5 = adjB[j + 5], i6 = adjB[j + 6], i7 = adjB[j + 7];
            u32 v0 = *(const u32*)&Hb[(size_t)i0 * 128 + lane * 2];
            u32 v1 = *(const u32*)&Hb[(size_t)i1 * 128 + lane * 2];
            u32 v2 = *(const u32*)&Hb[(size_t)i2 * 128 + lane * 2];
            u32 v3 = *(const u32*)&Hb[(size_t)i3 * 128 + lane * 2];
            u32 v4 = *(const u32*)&Hb[(size_t)i4 * 128 + lane * 2];
            u32 v5 = *(const u32*)&Hb[(size_t)i5 * 128 + lane * 2];
            u32 v6 = *(const u32*)&Hb[(size_t)i6 * 128 + lane * 2];
            u32 v7 = *(const u32*)&Hb[(size_t)i7 * 128 + lane * 2];
            s0 += ((bf_lo(v0) + bf_lo(v1)) + (bf_lo(v2) + bf_lo(v3))) +
                  ((bf_lo(v4) + bf_lo(v5)) + (bf_lo(v6) + bf_lo(v7)));
            s1 += ((bf_hi(v0) + bf_hi(v1)) + (bf_hi(v2) + bf_hi(v3))) +
                  ((bf_hi(v4) + bf_hi(v5)) + (bf_hi(v6) + bf_hi(v7)));
        }
        for (; j < b1; j++) {
            u32 v = *(const u32*)&Hb[(size_t)adjB[j] * 128 + lane * 2];
            s0 += bf_lo(v);
            s1 += bf_hi(v);
        }
        deg += b1 - b0;
    }
    float inv = deg ? 1.f / (float)deg : 0.f;
    u32 p = f2bf(s0 * inv) | (f2bf(s1 * inv) << 16);
    *(u32*)&outb[(size_t)node * 128 + lane * 2] = p;
}

// MFMA dual-GEMM: Out[n,0:128] = act(A[n,:K]@W1^T + B[n,:K]@W2^T + bias).
// A,B: bf16 [n][K]; W1,W2: bf16 [128][K] (UNtransposed — W[j][k] k-contiguous
// is exactly the 16x16x32 B-fragment layout). 4 waves/block, wave = 16 rows x
// 128 cols. A-frags in registers; no LDS.
// Frag layouts (gfx950 16x16x32 bf16): A: row=lane&15, k=8*(lane>>4)+j;
// B: col=lane&15, k=8*(lane>>4)+j; C/D: col=lane&15, row=(lane>>4)*4+reg [m89].
template <int KC, int OUT_BF16>  // KC = K/32
__global__ void __launch_bounds__(256) k_gemm_mfma(
        const u16* __restrict__ A, const u16* __restrict__ B,
        const u16* __restrict__ W1, const u16* __restrict__ W2,
        const float* __restrict__ bias,
        float* __restrict__ OutF, int ldo, u16* __restrict__ OutB,
        int n, int relu) {
    constexpr int K = KC * 32;
    const int lane = threadIdx.x & 63;
    const int wave = threadIdx.x >> 6;
    const int r0 = blockIdx.x * 64 + wave * 16;
    const int arow = r0 + (lane & 15);
    const size_t abase = (size_t)(arow < n ? arow : n - 1) * K;
    const int kof = (lane >> 4) * 8;

    bf16x8 a1[KC], a2[KC];
#pragma unroll
    for (int kc = 0; kc < KC; kc++) {
        a1[kc] = *(const bf16x8*)&A[abase + kc * 32 + kof];
        a2[kc] = *(const bf16x8*)&B[abase + kc * 32 + kof];
    }
    const int wr = lane & 15;
    const int rbase = r0 + (lane >> 4) * 4;
#pragma unroll
    for (int c = 0; c < 8; c++) {
        f32x4 acc = {0.f, 0.f, 0.f, 0.f};
        const size_t wof = (size_t)(c * 16 + wr) * K + kof;
#pragma unroll
        for (int kc = 0; kc < KC; kc++) {
            acc = __builtin_amdgcn_mfma_f32_16x16x32_bf16(
                a1[kc], *(const bf16x8*)&W1[wof + kc * 32], acc, 0, 0, 0);
            acc = __builtin_amdgcn_mfma_f32_16x16x32_bf16(
                a2[kc], *(const bf16x8*)&W2[wof + kc * 32], acc, 0, 0, 0);
        }
        const int col = c * 16 + wr;
        const float bv = bias[col];
#pragma unroll
        for (int r = 0; r < 4; r++) {
            const int row = rbase + r;
            if (row < n) {
                float v = acc[r] + bv;
                if (relu) v = fmaxf(v, 0.f);
                if (OUT_BF16) OutB[(size_t)row * 128 + col] = (u16)f2bf(v);
                else OutF[(size_t)row * ldo + col] = v;
            }
        }
    }
}

extern "C" void kernel_launch(void* const* d_in, const int* in_sizes, int n_in,
                              void* d_out, int out_size, void* d_ws, size_t ws_size,
                              hipStream_t stream) {
    const float* x = (const float*)d_in[0];
    const int* src = (const int*)d_in[1];
    const int* dst = (const int*)d_in[2];
    const float* Wn0 = (const float*)d_in[3];
    const float* Ws0 = (const float*)d_in[4];
    const float* b0 = (const float*)d_in[5];
    const float* Wn1 = (const float*)d_in[6];
    const float* Ws1 = (const float*)d_in[7];
    const float* b1 = (const float*)d_in[8];

    const int N = in_sizes[0] / 64;
    const int E = in_sizes[1];
    float* out = (float*)d_out;
    const int NB = (N + 255) >> 8;  // buckets of 256 nodes (must be <= 512)

    // ---- workspace layout ----
    char* w = (char*)d_ws;
    size_t o = 0;
    auto alloc = [&](size_t bytes) -> void* {
        o = (o + 255) & ~(size_t)255;
        void* p = w + o;
        o += bytes;
        return p;
    };
    int* off_in = (int*)alloc((size_t)(N + 1) * 4);
    int* off_out = (int*)alloc((size_t)(N + 1) * 4);
    int* cntD = (int*)alloc(512 * 4);
    int* cntS = (int*)alloc(512 * 4);
    int* curD = (int*)alloc(512 * 4);
    int* curS = (int*)alloc(512 * 4);
    int* bbaseD = (int*)alloc(513 * 4);
    int* bbaseS = (int*)alloc(513 * 4);
    int* adj_in = (int*)alloc((size_t)E * 4);
    int* adj_out = (int*)alloc((size_t)E * 4);
    u16* AGGb = (u16*)alloc((size_t)N * 128 * 2);  // L1 agg; L0 uses as 2x[N][64]
    u16* h1b = (u16*)alloc((size_t)N * 128 * 2);
    u16* u1b = (u16*)alloc((size_t)N * 128 * 2);
    u16* Wsb0 = (u16*)alloc(2 * 128 * 64 * 2);
    u16* Wnb0 = (u16*)alloc(2 * 128 * 64 * 2);
    u16* Wsb1 = (u16*)alloc(2 * 128 * 128 * 2);
    u16* Wnb1 = (u16*)alloc(2 * 128 * 128 * 2);
    (void)ws_size;

    // pair arrays alias h1b/u1b (dead until the L0 gemms run, after pass D)
    u32* pairsD = (u32*)h1b;
    u32* pairsS = (u32*)u1b;
    // xb (bf16 [N][64]) lives in d_out scratch (dead before final L1 writes)
    u16* xb = (u16*)d_out;

    const int n4 = N * 64 / 4;
    const int edgeBlocks = ((E + 7) / 8 + 255) / 256;

    // ---- fused prep: x->bf16 + 4 weight bf16 conversions ----
    k_prep<<<(n4 + 98304 + 255) / 256, 256, 0, stream>>>(x, xb, n4, Ws0, Wn0, Ws1, Wn1,
                                                         Wsb0, Wnb0, Wsb1, Wnb1);

    // ---- CSR build via bucketed counting sort ----
    k_zero<<<(1024 + 255) / 256, 256, 0, stream>>>(cntD, 1024);  // cntD+cntS contiguous
    k_bincnt<<<edgeBlocks, 256, 0, stream>>>(src, dst, cntD, cntS, E, NB);
    k_binscan<<<1, 512, 0, stream>>>(cntD, cntS, bbaseD, bbaseS, curD, curS,
                                     off_in, off_out, NB, N, E);
    k_binscatter<<<edgeBlocks, 256, 0, stream>>>(src, dst, curD, curS, pairsD, pairsS, E, NB);
    k_bucket_csr<<<2 * NB, 256, 0, stream>>>(pairsD, pairsS, bbaseD, bbaseS,
                                             off_in, adj_in, off_out, adj_out, N);

    const int nodeBlocks = (N + 3) / 4;
    const int gemmBlocks = (N + 63) / 64;

    // ---- layer 0 ----
    u16* agg0b = AGGb;                    // [N][64]
    u16* aggUb = AGGb + (size_t)N * 64;   // [N][64]
    k_agg_l0_b<<<nodeBlocks, 256, 0, stream>>>(xb, off_in, adj_in, off_out, adj_out,
                                               agg0b, aggUb, N);
    k_gemm_mfma<2, 1><<<gemmBlocks, 256, 0, stream>>>(xb, agg0b, Wsb0, Wnb0, b0,
                                                      (float*)nullptr, 0, h1b, N, 1);
    k_gemm_mfma<2, 1><<<gemmBlocks, 256, 0, stream>>>(xb, aggUb, Wsb0 + 128 * 64,
                                                      Wnb0 + 128 * 64, b0 + 128,
                                                      (float*)nullptr, 0, u1b, N, 1);

    // ---- layer 1 ----
    // head0: 'I' -> aggregate h1 over out-edges
    k_agg_l1_b<<<nodeBlocks, 256, 0, stream>>>(h1b, off_out, adj_out, (const int*)nullptr,
                                               (const int*)nullptr, AGGb, N);
    k_gemm_mfma<4, 0><<<gemmBlocks, 256, 0, stream>>>(h1b, AGGb, Wsb1, Wnb1, b1,
                                                      out, 256, (u16*)nullptr, N, 0);
    // head1: 'U' -> aggregate u1 over in+out edges
    k_agg_l1_b<<<nodeBlocks, 256, 0, stream>>>(u1b, off_in, adj_in, off_out, adj_out, AGGb, N);
    k_gemm_mfma<4, 0><<<gemmBlocks, 256, 0, stream>>>(u1b, AGGb, Wsb1 + 128 * 128,
                                                      Wnb1 + 128 * 128, b1 + 128,
                                                      out + 128, 256, (u16*)nullptr, N, 0);
}